// Round 4
// baseline (3375.487 us; speedup 1.0000x reference)
//
#include <hip/hip_runtime.h>
#include <hip/hip_bf16.h>
#include <cstdint>
#include <cstddef>

#define D 64
#define V_N 4000
#define E_N 40000
#define G_N 40
#define NPG 100          // nodes per graph (contiguous)
#define NODE_IN 74
#define EDGE_IN 128
#define NSTEPS 6
#define S2S_ITERS 6

typedef unsigned short u16b;

__device__ __forceinline__ float b2f(u16b u) {
  union { unsigned int i; float f; } v; v.i = ((unsigned int)u) << 16; return v.f;
}
__device__ __forceinline__ u16b f2b(float f) {
  union { unsigned int i; float f; } v; v.f = f;
  unsigned int r = (v.i + 0x7fffu + ((v.i >> 16) & 1u)) >> 16;
  return (u16b)r;
}
__device__ __forceinline__ float sigf(float x) { return 1.f / (1.f + expf(-x)); }

// ---------------- h = relu(node_feats @ W_proj + b_proj) ----------------
__global__ void k_proj(const float* __restrict__ nf, const float* __restrict__ W,
                       const float* __restrict__ b, float* __restrict__ h) {
  int v = blockIdx.x, o = threadIdx.x;            // 64 threads
  const float* row = nf + v * NODE_IN;
  float acc = b[o];
  for (int i = 0; i < NODE_IN; ++i)
    acc += row[i] * W[i * D + o];
  h[v * D + o] = fmaxf(acc, 0.f);
}

// ------- prep: GRU weight transpose -------
__global__ void k_prep(const float* __restrict__ W_ih, const float* __restrict__ W_hh,
                       float* __restrict__ WtIH, float* __restrict__ WtHH) {
  int idx = blockIdx.x * 256 + threadIdx.x;       // 192*64 = 12288
  if (idx < 192 * 64) {
    int j = idx >> 6, i = idx & 63;
    WtIH[i * 192 + j] = W_ih[j * 64 + i];
    WtHH[i * 192 + j] = W_hh[j * 64 + i];
  }
}

// ---------------- r1 = relu(edge_feats @ W_e1 + b_e1) -> bf16 ----------------
__global__ void k_edge1(const float* __restrict__ ef, const float* __restrict__ W,
                        const float* __restrict__ b, u16b* __restrict__ r1b) {
  __shared__ float x[8][EDGE_IN];
  int t = threadIdx.x;                            // 128 threads
  int e0 = blockIdx.x * 8;
  for (int e = 0; e < 8; ++e)
    x[e][t] = ef[(e0 + e) * EDGE_IN + t];
  __syncthreads();
  float acc[8];
  float bb = b[t];
#pragma unroll
  for (int e = 0; e < 8; ++e) acc[e] = bb;
  for (int i = 0; i < EDGE_IN; ++i) {
    float w = W[i * 128 + t];
#pragma unroll
    for (int e = 0; e < 8; ++e) acc[e] += x[e][i] * w;
  }
  for (int e = 0; e < 8; ++e)
    r1b[(e0 + e) * 128 + t] = f2b(fmaxf(acc[e], 0.f));
}

// ---------------- counting sort of edges by src ----------------
__global__ void k_zero(int* __restrict__ cnt) {   // 4096 bins
  cnt[blockIdx.x * 256 + threadIdx.x] = 0;
}
__global__ void k_hist(const int* __restrict__ src, int* __restrict__ cnt) {
  int e = blockIdx.x * 256 + threadIdx.x;
  if (e < E_N) atomicAdd(&cnt[src[e]], 1);
}
__global__ __launch_bounds__(256) void k_scan(const int* __restrict__ cnt,
                                              int* __restrict__ offs,
                                              int* __restrict__ cursor) {
  __shared__ int part[256];
  int t = threadIdx.x;                            // single block
  int local[16], s = 0;
#pragma unroll
  for (int b = 0; b < 16; ++b) { local[b] = cnt[t * 16 + b]; s += local[b]; }
  part[t] = s;
  __syncthreads();
  for (int off = 1; off < 256; off <<= 1) {
    int v = (t >= off) ? part[t - off] : 0;
    __syncthreads();
    part[t] += v;
    __syncthreads();
  }
  int run = part[t] - s;                          // exclusive base
#pragma unroll
  for (int b = 0; b < 16; ++b) {
    offs[t * 16 + b] = run;
    cursor[t * 16 + b] = run;
    run += local[b];
  }
}
__global__ void k_scatter(const int* __restrict__ src, int* __restrict__ cursor,
                          int* __restrict__ order) {
  int e = blockIdx.x * 256 + threadIdx.x;
  if (e < E_N) {
    int pos = atomicAdd(&cursor[src[e]], 1);
    order[pos] = e;
  }
}

// ---------------- Ybias[v][o] = sum_i h[v][i] * b_e2[i*64+o] ----------------
__global__ void k_ybias(const float* __restrict__ h, const float* __restrict__ b_e2,
                        float* __restrict__ Ybias) {
  int v = blockIdx.x, o = threadIdx.x;            // 64 threads
  float acc = 0.f;
  for (int i = 0; i < D; ++i)
    acc += h[v * D + i] * b_e2[i * 64 + o];
  Ybias[v * D + o] = acc;
}

// ---------------- agg init: agg[v][o] = b_conv[o] ----------------
__global__ void k_init_agg(float* __restrict__ agg, const float* __restrict__ b_conv) {
  int idx = blockIdx.x * 256 + threadIdx.x;
  agg[idx] = b_conv[idx & 63];
}

// ------ block per src node: T = h_v-contraction of W_e2; then its edges ------
__global__ __launch_bounds__(256) void k_msg2(
    const float* __restrict__ h, const u16b* __restrict__ r1b,
    const float* __restrict__ W2, const float* __restrict__ Ybias,
    const int* __restrict__ offs, const int* __restrict__ order,
    const int* __restrict__ dst, float* __restrict__ agg) {
  __shared__ float hv[D];
  __shared__ float T[EDGE_IN * D];                // 32 KB
  __shared__ float rrow[4][EDGE_IN];
  int t = threadIdx.x, v = blockIdx.x;
  int o = t & 63, w = t >> 6;
  if (t < D) hv[t] = h[v * D + t];
  __syncthreads();
  // T[k][o] = sum_i hv[i] * W2[k*4096 + i*64 + o];  wave w covers k in [w*32, w*32+32)
#pragma unroll 1
  for (int j = 0; j < 32; ++j) {
    int k = w * 32 + j;
    const float* wp = W2 + k * 4096 + o;
    float acc = 0.f;
#pragma unroll
    for (int i = 0; i < D; i += 4) {
      float4 h4 = *(const float4*)&hv[i];
      acc += h4.x * wp[i * 64] + h4.y * wp[(i + 1) * 64]
           + h4.z * wp[(i + 2) * 64] + h4.w * wp[(i + 3) * 64];
    }
    T[k * 64 + o] = acc;
  }
  __syncthreads();
  int e0 = offs[v], e1 = offs[v + 1];
  float ybv = Ybias[v * 64 + o];
  for (int j = e0 + w; j < e1; j += 4) {          // each wave takes its own edges
    int e = order[j];
    rrow[w][o] = b2f(r1b[e * 128 + o]);
    rrow[w][64 + o] = b2f(r1b[e * 128 + 64 + o]);
    float acc = ybv;
#pragma unroll 8
    for (int k = 0; k < 128; k += 4) {
      float4 rv = *(const float4*)&rrow[w][k];
      acc += rv.x * T[(k + 0) * 64 + o] + rv.y * T[(k + 1) * 64 + o]
           + rv.z * T[(k + 2) * 64 + o] + rv.w * T[(k + 3) * 64 + o];
    }
    atomicAdd(&agg[dst[e] * 64 + o], acc);
  }
}

// ---------------- GRU cell, in-place on h ----------------
__global__ void k_gru(const float* __restrict__ agg, float* __restrict__ h,
                      const float* __restrict__ WtIH, const float* __restrict__ WtHH,
                      const float* __restrict__ b_ih, const float* __restrict__ b_hh) {
  int v = blockIdx.x, o = threadIdx.x;            // 64 threads = 1 wave
  __shared__ float x[D], hp[D];
  x[o] = fmaxf(agg[v * D + o], 0.f);
  hp[o] = h[v * D + o];
  __syncthreads();
  float gr = b_ih[o],     gz = b_ih[D + o],  gn = b_ih[2 * D + o];
  float hr = b_hh[o],     hz = b_hh[D + o],  hn = b_hh[2 * D + o];
  for (int i = 0; i < D; ++i) {
    float xi = x[i], hi = hp[i];
    const float* wi = WtIH + i * 192;
    const float* wh = WtHH + i * 192;
    gr += wi[o] * xi;       gz += wi[D + o] * xi;       gn += wi[2 * D + o] * xi;
    hr += wh[o] * hi;       hz += wh[D + o] * hi;       hn += wh[2 * D + o] * hi;
  }
  float r = sigf(gr + hr);
  float z = sigf(gz + hz);
  float n = tanhf(gn + r * hn);
  h[v * D + o] = (1.f - z) * n + z * hp[o];
}

// ---------------- Set2Set (6 iters, 3-layer LSTM) + predict head ----------------
__global__ __launch_bounds__(256) void k_s2s(
    const float* __restrict__ h,
    const float* Wih0, const float* Whh0, const float* bih0, const float* bhh0,
    const float* Wih1, const float* Whh1, const float* bih1, const float* bhh1,
    const float* Wih2, const float* Whh2, const float* bih2, const float* bhh2,
    const float* W_p1, const float* b_p1, const float* W_p2, const float* b_p2,
    float* __restrict__ out) {
  int g = blockIdx.x, t = threadIdx.x;            // 256 threads
  __shared__ float hsL[3][D], csL[3][D], q_star[2 * D], gates[4 * D], att[NPG], scal[2];
  const float* hb = h + (size_t)g * NPG * D;
  if (t < D) {
    hsL[0][t] = 0.f; hsL[1][t] = 0.f; hsL[2][t] = 0.f;
    csL[0][t] = 0.f; csL[1][t] = 0.f; csL[2][t] = 0.f;
  }
  if (t < 2 * D) q_star[t] = 0.f;
  __syncthreads();
  for (int it = 0; it < S2S_ITERS; ++it) {
    for (int l = 0; l < 3; ++l) {
      const float* Wih = (l == 0) ? Wih0 : ((l == 1) ? Wih1 : Wih2);
      const float* Whh = (l == 0) ? Whh0 : ((l == 1) ? Whh1 : Whh2);
      const float* bih = (l == 0) ? bih0 : ((l == 1) ? bih1 : bih2);
      const float* bhh = (l == 0) ? bhh0 : ((l == 1) ? bhh1 : bhh2);
      const float* xin = (l == 0) ? q_star : hsL[l - 1];
      int in_dim = (l == 0) ? 2 * D : D;
      float gacc = bih[t] + bhh[t];
      const float* wr = Wih + t * in_dim;
      for (int k = 0; k < in_dim; ++k) gacc += wr[k] * xin[k];
      const float* hr = Whh + t * D;
      const float* hh = hsL[l];
      for (int k = 0; k < D; ++k) gacc += hr[k] * hh[k];
      gates[t] = gacc;
      __syncthreads();
      if (t < D) {
        float ig = gates[t], fg = gates[D + t], gg = gates[2 * D + t], og = gates[3 * D + t];
        float c = sigf(fg) * csL[l][t] + sigf(ig) * tanhf(gg);
        csL[l][t] = c;
        hsL[l][t] = sigf(og) * tanhf(c);
      }
      __syncthreads();
    }
    if (t < NPG) {
      float e = 0.f;
      for (int dd = 0; dd < D; ++dd) e += hb[t * D + dd] * hsL[2][dd];
      att[t] = e;
    }
    __syncthreads();
    if (t == 0) {
      float m = att[0];
      for (int n = 1; n < NPG; ++n) m = fmaxf(m, att[n]);
      scal[0] = m;
    }
    __syncthreads();
    if (t < NPG) att[t] = expf(att[t] - scal[0]);
    __syncthreads();
    if (t == 0) {
      float s = 0.f;
      for (int n = 0; n < NPG; ++n) s += att[n];
      scal[1] = 1.f / s;
    }
    __syncthreads();
    if (t < D) {
      float inv = scal[1];
      float r = 0.f;
      for (int n = 0; n < NPG; ++n) r += hb[n * D + t] * att[n];
      q_star[t] = hsL[2][t];
      q_star[D + t] = r * inv;
    }
    __syncthreads();
  }
  if (t < D) {
    float p = b_p1[t];
    for (int k = 0; k < 2 * D; ++k) p += q_star[k] * W_p1[k * D + t];
    p = fmaxf(p, 0.f);
    att[t] = p * W_p2[t];
  }
  __syncthreads();
  if (t == 0) {
    float s = 0.f;
    for (int j = 0; j < D; ++j) s += att[j];
    out[g] = s + b_p2[0];
  }
}

extern "C" void kernel_launch(void* const* d_in, const int* in_sizes, int n_in,
                              void* d_out, int out_size, void* d_ws, size_t ws_size,
                              hipStream_t stream) {
  const float* node_feats = (const float*)d_in[0];
  const float* edge_feats = (const float*)d_in[1];
  const int*   src        = (const int*)d_in[2];
  const int*   dst        = (const int*)d_in[3];
  // d_in[4] graph_ids: contiguous 100-node segments by construction
  const float* W_proj = (const float*)d_in[5];
  const float* b_proj = (const float*)d_in[6];
  const float* W_e1   = (const float*)d_in[7];
  const float* b_e1   = (const float*)d_in[8];
  const float* W_e2   = (const float*)d_in[9];
  const float* b_e2   = (const float*)d_in[10];
  const float* b_conv = (const float*)d_in[11];
  const float* W_ih   = (const float*)d_in[12];
  const float* W_hh   = (const float*)d_in[13];
  const float* b_ih   = (const float*)d_in[14];
  const float* b_hh   = (const float*)d_in[15];
  const float* Wih0 = (const float*)d_in[16]; const float* Whh0 = (const float*)d_in[17];
  const float* bih0 = (const float*)d_in[18]; const float* bhh0 = (const float*)d_in[19];
  const float* Wih1 = (const float*)d_in[20]; const float* Whh1 = (const float*)d_in[21];
  const float* bih1 = (const float*)d_in[22]; const float* bhh1 = (const float*)d_in[23];
  const float* Wih2 = (const float*)d_in[24]; const float* Whh2 = (const float*)d_in[25];
  const float* bih2 = (const float*)d_in[26]; const float* bhh2 = (const float*)d_in[27];
  const float* W_p1 = (const float*)d_in[28]; const float* b_p1 = (const float*)d_in[29];
  const float* W_p2 = (const float*)d_in[30]; const float* b_p2 = (const float*)d_in[31];

  // ---- workspace layout (total ~13.6 MB) ----
  char* ws = (char*)d_ws;
  float* h      = (float*)(ws + 0);               // 1,024,000
  float* agg    = (float*)(ws + 1024000);         // 1,024,000
  u16b*  r1b    = (u16b*) (ws + 2048000);         // 10,240,000
  float* Ybias  = (float*)(ws + 12288000);        // 1,024,000
  float* WtIH   = (float*)(ws + 13312000);        // 49,152
  float* WtHH   = (float*)(ws + 13361152);        // 49,152
  int*   offs   = (int*)  (ws + 13410304);        // 16,384 (4096 bins)
  int*   cursor = (int*)  (ws + 13426688);        // 16,384
  int*   order  = (int*)  (ws + 13443072);        // 160,000 -> end 13,603,072

  k_proj<<<V_N, 64, 0, stream>>>(node_feats, W_proj, b_proj, h);
  k_prep<<<48, 256, 0, stream>>>(W_ih, W_hh, WtIH, WtHH);
  k_edge1<<<E_N / 8, 128, 0, stream>>>(edge_feats, W_e1, b_e1, r1b);
  // counting sort by src (uses cursor as counts first)
  k_zero<<<16, 256, 0, stream>>>(cursor);
  k_hist<<<(E_N + 255) / 256, 256, 0, stream>>>(src, cursor);
  k_scan<<<1, 256, 0, stream>>>(cursor, offs, cursor);
  k_scatter<<<(E_N + 255) / 256, 256, 0, stream>>>(src, cursor, order);

  for (int s = 0; s < NSTEPS; ++s) {
    k_ybias<<<V_N, 64, 0, stream>>>(h, b_e2, Ybias);
    k_init_agg<<<(V_N * D) / 256, 256, 0, stream>>>(agg, b_conv);
    k_msg2<<<V_N, 256, 0, stream>>>(h, r1b, W_e2, Ybias, offs, order, dst, agg);
    k_gru<<<V_N, 64, 0, stream>>>(agg, h, WtIH, WtHH, b_ih, b_hh);
  }
  k_s2s<<<G_N, 256, 0, stream>>>(h,
      Wih0, Whh0, bih0, bhh0, Wih1, Whh1, bih1, bhh1, Wih2, Whh2, bih2, bhh2,
      W_p1, b_p1, W_p2, b_p2, (float*)d_out);
}

// Round 5
// 1554.131 us; speedup vs baseline: 2.1719x; 2.1719x over previous
//
#include <hip/hip_runtime.h>
#include <hip/hip_bf16.h>
#include <cstdint>
#include <cstddef>

#define D 64
#define V_N 4000
#define E_N 40000
#define G_N 40
#define NPG 100          // nodes per graph (contiguous)
#define NODE_IN 74
#define EDGE_IN 128
#define NSTEPS 6
#define S2S_ITERS 6

typedef unsigned short u16b;

__device__ __forceinline__ float b2f(u16b u) {
  union { unsigned int i; float f; } v; v.i = ((unsigned int)u) << 16; return v.f;
}
__device__ __forceinline__ u16b f2b(float f) {
  union { unsigned int i; float f; } v; v.f = f;
  unsigned int r = (v.i + 0x7fffu + ((v.i >> 16) & 1u)) >> 16;
  return (u16b)r;
}
__device__ __forceinline__ float sigf(float x) { return 1.f / (1.f + expf(-x)); }

// ---------------- h = relu(node_feats @ W_proj + b_proj) ----------------
__global__ void k_proj(const float* __restrict__ nf, const float* __restrict__ W,
                       const float* __restrict__ b, float* __restrict__ h) {
  int v = blockIdx.x, o = threadIdx.x;            // 64 threads
  const float* row = nf + v * NODE_IN;
  float acc = b[o];
  for (int i = 0; i < NODE_IN; ++i)
    acc += row[i] * W[i * D + o];
  h[v * D + o] = fmaxf(acc, 0.f);
}

// ------- prep: GRU weight transpose -------
__global__ void k_prep(const float* __restrict__ W_ih, const float* __restrict__ W_hh,
                       float* __restrict__ WtIH, float* __restrict__ WtHH) {
  int idx = blockIdx.x * 256 + threadIdx.x;       // 192*64 = 12288
  if (idx < 192 * 64) {
    int j = idx >> 6, i = idx & 63;
    WtIH[i * 192 + j] = W_ih[j * 64 + i];
    WtHH[i * 192 + j] = W_hh[j * 64 + i];
  }
}

// ---------------- r1 = relu(edge_feats @ W_e1 + b_e1) -> bf16 ----------------
__global__ void k_edge1(const float* __restrict__ ef, const float* __restrict__ W,
                        const float* __restrict__ b, u16b* __restrict__ r1b) {
  __shared__ float x[8][EDGE_IN];
  int t = threadIdx.x;                            // 128 threads
  int e0 = blockIdx.x * 8;
  for (int e = 0; e < 8; ++e)
    x[e][t] = ef[(e0 + e) * EDGE_IN + t];
  __syncthreads();
  float acc[8];
  float bb = b[t];
#pragma unroll
  for (int e = 0; e < 8; ++e) acc[e] = bb;
  for (int i = 0; i < EDGE_IN; ++i) {
    float w = W[i * 128 + t];
#pragma unroll
    for (int e = 0; e < 8; ++e) acc[e] += x[e][i] * w;
  }
  for (int e = 0; e < 8; ++e)
    r1b[(e0 + e) * 128 + t] = f2b(fmaxf(acc[e], 0.f));
}

// ---------------- counting sort of edges by src ----------------
__global__ void k_zero(int* __restrict__ cnt) {   // 4096 bins
  cnt[blockIdx.x * 256 + threadIdx.x] = 0;
}
__global__ void k_hist(const int* __restrict__ src, int* __restrict__ cnt) {
  int e = blockIdx.x * 256 + threadIdx.x;
  if (e < E_N) atomicAdd(&cnt[src[e]], 1);
}
__global__ __launch_bounds__(256) void k_scan(const int* __restrict__ cnt,
                                              int* __restrict__ offs,
                                              int* __restrict__ cursor) {
  __shared__ int part[256];
  int t = threadIdx.x;                            // single block
  int local[16], s = 0;
#pragma unroll
  for (int b = 0; b < 16; ++b) { local[b] = cnt[t * 16 + b]; s += local[b]; }
  part[t] = s;
  __syncthreads();
  for (int off = 1; off < 256; off <<= 1) {
    int v = (t >= off) ? part[t - off] : 0;
    __syncthreads();
    part[t] += v;
    __syncthreads();
  }
  int run = part[t] - s;                          // exclusive base
#pragma unroll
  for (int b = 0; b < 16; ++b) {
    offs[t * 16 + b] = run;
    cursor[t * 16 + b] = run;
    run += local[b];
  }
}
__global__ void k_scatter(const int* __restrict__ src, int* __restrict__ cursor,
                          int* __restrict__ order) {
  int e = blockIdx.x * 256 + threadIdx.x;
  if (e < E_N) {
    int pos = atomicAdd(&cursor[src[e]], 1);
    order[pos] = e;
  }
}

// ---------------- Ybias[v][o] = sum_i h[v][i] * b_e2[i*64+o] ----------------
__global__ void k_ybias(const float* __restrict__ h, const float* __restrict__ b_e2,
                        float* __restrict__ Ybias) {
  int v = blockIdx.x, o = threadIdx.x;            // 64 threads
  float acc = 0.f;
  for (int i = 0; i < D; ++i)
    acc += h[v * D + i] * b_e2[i * 64 + o];
  Ybias[v * D + o] = acc;
}

// ---------------- agg init: agg[v][o] = b_conv[o] ----------------
__global__ void k_init_agg(float* __restrict__ agg, const float* __restrict__ b_conv) {
  int idx = blockIdx.x * 256 + threadIdx.x;
  agg[idx] = b_conv[idx & 63];
}

// ------ block = 2 src nodes. Phase A: T[n][k*64+o] via float4 W2 loads.
// ------ Phase B: per-edge dot(r1, T) via __shfl broadcast, atomic scatter.
__global__ __launch_bounds__(256) void k_msg3(
    const float* __restrict__ h, const u16b* __restrict__ r1b,
    const float* __restrict__ W2, const float* __restrict__ Ybias,
    const int* __restrict__ offs, const int* __restrict__ order,
    const int* __restrict__ dst, float* __restrict__ agg) {
  __shared__ float T[2][8192];                    // 64 KB exactly
  int t = threadIdx.x;
  int v0 = blockIdx.x * 2;
  const float* h0 = h + v0 * 64;                  // wave-uniform -> scalar loads
  const float* h1 = h + v0 * 64 + 64;
  // Phase A: thread t owns pairs P=j*256+t; P -> (k=P>>4, o4=P&15);
  // T flat offset = k*64 + o4*4 = 4*P. Lane groups of 16 read contiguous 256B.
#pragma unroll
  for (int jc = 0; jc < 4; ++jc) {
    float a00[4] = {0,0,0,0}, a01[4] = {0,0,0,0}; // [cp=0][n], 4 o-components
    float a10[4] = {0,0,0,0}, a11[4] = {0,0,0,0}; // [cp=1][n]
    int P0 = (jc * 2 + 0) * 256 + t;
    int P1 = (jc * 2 + 1) * 256 + t;
    const float* b0 = W2 + (size_t)(P0 >> 4) * 4096 + (P0 & 15) * 4;
    const float* b1 = W2 + (size_t)(P1 >> 4) * 4096 + (P1 & 15) * 4;
#pragma unroll 8
    for (int i = 0; i < 64; ++i) {
      float hA = h0[i];                           // uniform scalar
      float hB = h1[i];
      float4 w0 = *(const float4*)(b0 + i * 64);
      float4 w1 = *(const float4*)(b1 + i * 64);
      a00[0] += hA * w0.x; a00[1] += hA * w0.y; a00[2] += hA * w0.z; a00[3] += hA * w0.w;
      a01[0] += hB * w0.x; a01[1] += hB * w0.y; a01[2] += hB * w0.z; a01[3] += hB * w0.w;
      a10[0] += hA * w1.x; a10[1] += hA * w1.y; a10[2] += hA * w1.z; a10[3] += hA * w1.w;
      a11[0] += hB * w1.x; a11[1] += hB * w1.y; a11[2] += hB * w1.z; a11[3] += hB * w1.w;
    }
    *(float4*)&T[0][4 * P0] = make_float4(a00[0], a00[1], a00[2], a00[3]);
    *(float4*)&T[1][4 * P0] = make_float4(a01[0], a01[1], a01[2], a01[3]);
    *(float4*)&T[0][4 * P1] = make_float4(a10[0], a10[1], a10[2], a10[3]);
    *(float4*)&T[1][4 * P1] = make_float4(a11[0], a11[1], a11[2], a11[3]);
  }
  __syncthreads();
  // Phase B: waves 0,1 -> node v0; waves 2,3 -> node v0+1 (edge parity split)
  int w = t >> 6, o = t & 63;
  int n2 = w >> 1, wo = w & 1;
  int v = v0 + n2;
  int e0 = offs[v], e1 = offs[v + 1];
  float ybv = Ybias[v * 64 + o];
  const float* Tp = T[n2];
  for (int j = e0 + wo; j < e1; j += 2) {
    int e = order[j];
    float rlo = b2f(r1b[e * 128 + o]);            // r1[e][o]
    float rhi = b2f(r1b[e * 128 + 64 + o]);       // r1[e][64+o]
    float acc = ybv;
#pragma unroll 8
    for (int k = 0; k < 64; ++k)
      acc += __shfl(rlo, k) * Tp[k * 64 + o];
#pragma unroll 8
    for (int k = 0; k < 64; ++k)
      acc += __shfl(rhi, k) * Tp[(64 + k) * 64 + o];
    atomicAdd(&agg[dst[e] * 64 + o], acc);
  }
}

// ---------------- GRU cell, in-place on h ----------------
__global__ void k_gru(const float* __restrict__ agg, float* __restrict__ h,
                      const float* __restrict__ WtIH, const float* __restrict__ WtHH,
                      const float* __restrict__ b_ih, const float* __restrict__ b_hh) {
  int v = blockIdx.x, o = threadIdx.x;            // 64 threads = 1 wave
  __shared__ float x[D], hp[D];
  x[o] = fmaxf(agg[v * D + o], 0.f);
  hp[o] = h[v * D + o];
  __syncthreads();
  float gr = b_ih[o],     gz = b_ih[D + o],  gn = b_ih[2 * D + o];
  float hr = b_hh[o],     hz = b_hh[D + o],  hn = b_hh[2 * D + o];
  for (int i = 0; i < D; ++i) {
    float xi = x[i], hi = hp[i];
    const float* wi = WtIH + i * 192;
    const float* wh = WtHH + i * 192;
    gr += wi[o] * xi;       gz += wi[D + o] * xi;       gn += wi[2 * D + o] * xi;
    hr += wh[o] * hi;       hz += wh[D + o] * hi;       hn += wh[2 * D + o] * hi;
  }
  float r = sigf(gr + hr);
  float z = sigf(gz + hz);
  float n = tanhf(gn + r * hn);
  h[v * D + o] = (1.f - z) * n + z * hp[o];
}

// ---------------- Set2Set (6 iters, 3-layer LSTM) + predict head ----------------
__global__ __launch_bounds__(256) void k_s2s(
    const float* __restrict__ h,
    const float* Wih0, const float* Whh0, const float* bih0, const float* bhh0,
    const float* Wih1, const float* Whh1, const float* bih1, const float* bhh1,
    const float* Wih2, const float* Whh2, const float* bih2, const float* bhh2,
    const float* W_p1, const float* b_p1, const float* W_p2, const float* b_p2,
    float* __restrict__ out) {
  int g = blockIdx.x, t = threadIdx.x;            // 256 threads
  __shared__ float hsL[3][D], csL[3][D], q_star[2 * D], gates[4 * D], att[NPG], scal[2];
  const float* hb = h + (size_t)g * NPG * D;
  if (t < D) {
    hsL[0][t] = 0.f; hsL[1][t] = 0.f; hsL[2][t] = 0.f;
    csL[0][t] = 0.f; csL[1][t] = 0.f; csL[2][t] = 0.f;
  }
  if (t < 2 * D) q_star[t] = 0.f;
  __syncthreads();
  for (int it = 0; it < S2S_ITERS; ++it) {
    for (int l = 0; l < 3; ++l) {
      const float* Wih = (l == 0) ? Wih0 : ((l == 1) ? Wih1 : Wih2);
      const float* Whh = (l == 0) ? Whh0 : ((l == 1) ? Whh1 : Whh2);
      const float* bih = (l == 0) ? bih0 : ((l == 1) ? bih1 : bih2);
      const float* bhh = (l == 0) ? bhh0 : ((l == 1) ? bhh1 : bhh2);
      const float* xin = (l == 0) ? q_star : hsL[l - 1];
      int in_dim = (l == 0) ? 2 * D : D;
      float gacc = bih[t] + bhh[t];
      const float* wr = Wih + t * in_dim;
      for (int k = 0; k < in_dim; ++k) gacc += wr[k] * xin[k];
      const float* hr = Whh + t * D;
      const float* hh = hsL[l];
      for (int k = 0; k < D; ++k) gacc += hr[k] * hh[k];
      gates[t] = gacc;
      __syncthreads();
      if (t < D) {
        float ig = gates[t], fg = gates[D + t], gg = gates[2 * D + t], og = gates[3 * D + t];
        float c = sigf(fg) * csL[l][t] + sigf(ig) * tanhf(gg);
        csL[l][t] = c;
        hsL[l][t] = sigf(og) * tanhf(c);
      }
      __syncthreads();
    }
    if (t < NPG) {
      float e = 0.f;
      for (int dd = 0; dd < D; ++dd) e += hb[t * D + dd] * hsL[2][dd];
      att[t] = e;
    }
    __syncthreads();
    if (t == 0) {
      float m = att[0];
      for (int n = 1; n < NPG; ++n) m = fmaxf(m, att[n]);
      scal[0] = m;
    }
    __syncthreads();
    if (t < NPG) att[t] = expf(att[t] - scal[0]);
    __syncthreads();
    if (t == 0) {
      float s = 0.f;
      for (int n = 0; n < NPG; ++n) s += att[n];
      scal[1] = 1.f / s;
    }
    __syncthreads();
    if (t < D) {
      float inv = scal[1];
      float r = 0.f;
      for (int n = 0; n < NPG; ++n) r += hb[n * D + t] * att[n];
      q_star[t] = hsL[2][t];
      q_star[D + t] = r * inv;
    }
    __syncthreads();
  }
  if (t < D) {
    float p = b_p1[t];
    for (int k = 0; k < 2 * D; ++k) p += q_star[k] * W_p1[k * D + t];
    p = fmaxf(p, 0.f);
    att[t] = p * W_p2[t];
  }
  __syncthreads();
  if (t == 0) {
    float s = 0.f;
    for (int j = 0; j < D; ++j) s += att[j];
    out[g] = s + b_p2[0];
  }
}

extern "C" void kernel_launch(void* const* d_in, const int* in_sizes, int n_in,
                              void* d_out, int out_size, void* d_ws, size_t ws_size,
                              hipStream_t stream) {
  const float* node_feats = (const float*)d_in[0];
  const float* edge_feats = (const float*)d_in[1];
  const int*   src        = (const int*)d_in[2];
  const int*   dst        = (const int*)d_in[3];
  // d_in[4] graph_ids: contiguous 100-node segments by construction
  const float* W_proj = (const float*)d_in[5];
  const float* b_proj = (const float*)d_in[6];
  const float* W_e1   = (const float*)d_in[7];
  const float* b_e1   = (const float*)d_in[8];
  const float* W_e2   = (const float*)d_in[9];
  const float* b_e2   = (const float*)d_in[10];
  const float* b_conv = (const float*)d_in[11];
  const float* W_ih   = (const float*)d_in[12];
  const float* W_hh   = (const float*)d_in[13];
  const float* b_ih   = (const float*)d_in[14];
  const float* b_hh   = (const float*)d_in[15];
  const float* Wih0 = (const float*)d_in[16]; const float* Whh0 = (const float*)d_in[17];
  const float* bih0 = (const float*)d_in[18]; const float* bhh0 = (const float*)d_in[19];
  const float* Wih1 = (const float*)d_in[20]; const float* Whh1 = (const float*)d_in[21];
  const float* bih1 = (const float*)d_in[22]; const float* bhh1 = (const float*)d_in[23];
  const float* Wih2 = (const float*)d_in[24]; const float* Whh2 = (const float*)d_in[25];
  const float* bih2 = (const float*)d_in[26]; const float* bhh2 = (const float*)d_in[27];
  const float* W_p1 = (const float*)d_in[28]; const float* b_p1 = (const float*)d_in[29];
  const float* W_p2 = (const float*)d_in[30]; const float* b_p2 = (const float*)d_in[31];

  // ---- workspace layout (total ~13.6 MB, proven safe) ----
  char* ws = (char*)d_ws;
  float* h      = (float*)(ws + 0);               // 1,024,000
  float* agg    = (float*)(ws + 1024000);         // 1,024,000
  u16b*  r1b    = (u16b*) (ws + 2048000);         // 10,240,000
  float* Ybias  = (float*)(ws + 12288000);        // 1,024,000
  float* WtIH   = (float*)(ws + 13312000);        // 49,152
  float* WtHH   = (float*)(ws + 13361152);        // 49,152
  int*   offs   = (int*)  (ws + 13410304);        // 16,384 (4096 bins)
  int*   cursor = (int*)  (ws + 13426688);        // 16,384
  int*   order  = (int*)  (ws + 13443072);        // 160,000 -> end 13,603,072

  k_proj<<<V_N, 64, 0, stream>>>(node_feats, W_proj, b_proj, h);
  k_prep<<<48, 256, 0, stream>>>(W_ih, W_hh, WtIH, WtHH);
  k_edge1<<<E_N / 8, 128, 0, stream>>>(edge_feats, W_e1, b_e1, r1b);
  // counting sort by src (uses cursor as counts first)
  k_zero<<<16, 256, 0, stream>>>(cursor);
  k_hist<<<(E_N + 255) / 256, 256, 0, stream>>>(src, cursor);
  k_scan<<<1, 256, 0, stream>>>(cursor, offs, cursor);
  k_scatter<<<(E_N + 255) / 256, 256, 0, stream>>>(src, cursor, order);

  for (int s = 0; s < NSTEPS; ++s) {
    k_ybias<<<V_N, 64, 0, stream>>>(h, b_e2, Ybias);
    k_init_agg<<<(V_N * D) / 256, 256, 0, stream>>>(agg, b_conv);
    k_msg3<<<V_N / 2, 256, 0, stream>>>(h, r1b, W_e2, Ybias, offs, order, dst, agg);
    k_gru<<<V_N, 64, 0, stream>>>(agg, h, WtIH, WtHH, b_ih, b_hh);
  }
  k_s2s<<<G_N, 256, 0, stream>>>(h,
      Wih0, Whh0, bih0, bhh0, Wih1, Whh1, bih1, bhh1, Wih2, Whh2, bih2, bhh2,
      W_p1, b_p1, W_p2, b_p2, (float*)d_out);
}

// Round 6
// 1125.817 us; speedup vs baseline: 2.9983x; 1.3804x over previous
//
#include <hip/hip_runtime.h>
#include <hip/hip_bf16.h>
#include <cstdint>
#include <cstddef>

#define D 64
#define V_N 4000
#define E_N 40000
#define G_N 40
#define NPG 100          // nodes per graph (contiguous)
#define NODE_IN 74
#define EDGE_IN 128
#define NSTEPS 6
#define S2S_ITERS 6

typedef unsigned short u16b;

__device__ __forceinline__ float b2f(u16b u) {
  union { unsigned int i; float f; } v; v.i = ((unsigned int)u) << 16; return v.f;
}
__device__ __forceinline__ u16b f2b(float f) {
  union { unsigned int i; float f; } v; v.f = f;
  unsigned int r = (v.i + 0x7fffu + ((v.i >> 16) & 1u)) >> 16;
  return (u16b)r;
}
__device__ __forceinline__ float sigf(float x) { return 1.f / (1.f + expf(-x)); }
__device__ __forceinline__ float rdlane(float v, int l) {
  return __int_as_float(__builtin_amdgcn_readlane(__float_as_int(v), l));
}

// ---------------- h = relu(node_feats @ W_proj + b_proj) ----------------
__global__ void k_proj(const float* __restrict__ nf, const float* __restrict__ W,
                       const float* __restrict__ b, float* __restrict__ h) {
  int v = blockIdx.x, o = threadIdx.x;            // 64 threads
  const float* row = nf + v * NODE_IN;
  float acc = b[o];
  for (int i = 0; i < NODE_IN; ++i)
    acc += row[i] * W[i * D + o];
  h[v * D + o] = fmaxf(acc, 0.f);
}

// ------- prep: GRU weight transpose + W_e2 -> bf16 -------
__global__ void k_prep(const float* __restrict__ W_ih, const float* __restrict__ W_hh,
                       const float* __restrict__ W_e2,
                       float* __restrict__ WtIH, float* __restrict__ WtHH,
                       u16b* __restrict__ W2b) {
  int idx = blockIdx.x * 256 + threadIdx.x;       // grid covers 524288
  if (idx < 192 * 64) {
    int j = idx >> 6, i = idx & 63;
    WtIH[i * 192 + j] = W_ih[j * 64 + i];
    WtHH[i * 192 + j] = W_hh[j * 64 + i];
  }
  if (idx < EDGE_IN * D * D)
    W2b[idx] = f2b(W_e2[idx]);                    // [k][i*64+o] flat, bf16
}

// ---------------- r1 = relu(edge_feats @ W_e1 + b_e1) -> bf16 ----------------
__global__ void k_edge1(const float* __restrict__ ef, const float* __restrict__ W,
                        const float* __restrict__ b, u16b* __restrict__ r1b) {
  __shared__ float x[8][EDGE_IN];
  int t = threadIdx.x;                            // 128 threads
  int e0 = blockIdx.x * 8;
  for (int e = 0; e < 8; ++e)
    x[e][t] = ef[(e0 + e) * EDGE_IN + t];
  __syncthreads();
  float acc[8];
  float bb = b[t];
#pragma unroll
  for (int e = 0; e < 8; ++e) acc[e] = bb;
  for (int i = 0; i < EDGE_IN; ++i) {
    float w = W[i * 128 + t];
#pragma unroll
    for (int e = 0; e < 8; ++e) acc[e] += x[e][i] * w;
  }
  for (int e = 0; e < 8; ++e)
    r1b[(e0 + e) * 128 + t] = f2b(fmaxf(acc[e], 0.f));
}

// ---------------- counting sort of edges by src ----------------
__global__ void k_zero(int* __restrict__ cnt) {   // 4096 bins
  cnt[blockIdx.x * 256 + threadIdx.x] = 0;
}
__global__ void k_hist(const int* __restrict__ src, int* __restrict__ cnt) {
  int e = blockIdx.x * 256 + threadIdx.x;
  if (e < E_N) atomicAdd(&cnt[src[e]], 1);
}
__global__ __launch_bounds__(256) void k_scan(const int* __restrict__ cnt,
                                              int* __restrict__ offs,
                                              int* __restrict__ cursor) {
  __shared__ int part[256];
  int t = threadIdx.x;                            // single block
  int local[16], s = 0;
#pragma unroll
  for (int b = 0; b < 16; ++b) { local[b] = cnt[t * 16 + b]; s += local[b]; }
  part[t] = s;
  __syncthreads();
  for (int off = 1; off < 256; off <<= 1) {
    int v = (t >= off) ? part[t - off] : 0;
    __syncthreads();
    part[t] += v;
    __syncthreads();
  }
  int run = part[t] - s;                          // exclusive base
#pragma unroll
  for (int b = 0; b < 16; ++b) {
    offs[t * 16 + b] = run;
    cursor[t * 16 + b] = run;
    run += local[b];
  }
}
__global__ void k_scatter(const int* __restrict__ src, int* __restrict__ cursor,
                          int* __restrict__ order) {
  int e = blockIdx.x * 256 + threadIdx.x;
  if (e < E_N) {
    int pos = atomicAdd(&cursor[src[e]], 1);
    order[pos] = e;
  }
}

// ---------------- Ybias[v][o] = sum_i h[v][i] * b_e2[i*64+o] ----------------
__global__ void k_ybias(const float* __restrict__ h, const float* __restrict__ b_e2,
                        float* __restrict__ Ybias) {
  int v = blockIdx.x, o = threadIdx.x;            // 64 threads
  float acc = 0.f;
  for (int i = 0; i < D; ++i)
    acc += h[v * D + i] * b_e2[i * 64 + o];
  Ybias[v * D + o] = acc;
}

// ---------------- agg init: agg[v][o] = b_conv[o] ----------------
__global__ void k_init_agg(float* __restrict__ agg, const float* __restrict__ b_conv) {
  int idx = blockIdx.x * 256 + threadIdx.x;
  agg[idx] = b_conv[idx & 63];
}

// ------ block = 4 src nodes. Phase A: T[n][k][o] (bf16 LDS, 64 KB) from
// ------ bf16 W2 uint4 loads. Phase B: per-edge dot via readlane broadcast.
__global__ __launch_bounds__(256) void k_msg4(
    const float* __restrict__ h, const u16b* __restrict__ r1b,
    const uint4* __restrict__ W2b4, const float* __restrict__ Ybias,
    const int* __restrict__ offs, const int* __restrict__ order,
    const int* __restrict__ dst, float* __restrict__ agg) {
  __shared__ __align__(16) u16b T[4 * 8192];      // 64 KB exactly
  int t = threadIdx.x;
  int v0 = blockIdx.x * 4;
  int lane = t & 63;
  // preload h rows into lane-distributed registers (readlane broadcast later)
  float hreg[4];
#pragma unroll
  for (int n = 0; n < 4; ++n) hreg[n] = h[(v0 + n) * 64 + lane];
  // Phase A: slot = j*256+t -> k = slot>>3 (0..127), o8 = slot&7 (8 consecutive o)
#pragma unroll
  for (int j = 0; j < 4; ++j) {
    int slot = j * 256 + t;
    int k = slot >> 3, o8 = slot & 7;
    const uint4* wp = W2b4 + (size_t)k * 512;     // row = 4096 bf16 = 512 uint4
    float acc[4][8];
#pragma unroll
    for (int n = 0; n < 4; ++n)
#pragma unroll
      for (int q = 0; q < 8; ++q) acc[n][q] = 0.f;
    for (int i = 0; i < 64; ++i) {
      uint4 wv = wp[i * 8 + o8];
      float f0 = b2f((u16b)(wv.x & 0xffff)), f1 = b2f((u16b)(wv.x >> 16));
      float f2 = b2f((u16b)(wv.y & 0xffff)), f3 = b2f((u16b)(wv.y >> 16));
      float f4 = b2f((u16b)(wv.z & 0xffff)), f5 = b2f((u16b)(wv.z >> 16));
      float f6 = b2f((u16b)(wv.w & 0xffff)), f7 = b2f((u16b)(wv.w >> 16));
#pragma unroll
      for (int n = 0; n < 4; ++n) {
        float hn = rdlane(hreg[n], i);
        acc[n][0] += hn * f0; acc[n][1] += hn * f1;
        acc[n][2] += hn * f2; acc[n][3] += hn * f3;
        acc[n][4] += hn * f4; acc[n][5] += hn * f5;
        acc[n][6] += hn * f6; acc[n][7] += hn * f7;
      }
    }
#pragma unroll
    for (int n = 0; n < 4; ++n) {
      uint4 pk;
      pk.x = (unsigned)f2b(acc[n][0]) | ((unsigned)f2b(acc[n][1]) << 16);
      pk.y = (unsigned)f2b(acc[n][2]) | ((unsigned)f2b(acc[n][3]) << 16);
      pk.z = (unsigned)f2b(acc[n][4]) | ((unsigned)f2b(acc[n][5]) << 16);
      pk.w = (unsigned)f2b(acc[n][6]) | ((unsigned)f2b(acc[n][7]) << 16);
      *(uint4*)&T[n * 8192 + k * 64 + o8 * 8] = pk;
    }
  }
  __syncthreads();
  // Phase B: combined edge pool of the 4 nodes, wave w takes every 4th edge
  int w = t >> 6, o = lane;
  int e0 = offs[v0], e4 = offs[v0 + 4];
  int c1 = offs[v0 + 1], c2 = offs[v0 + 2], c3 = offs[v0 + 3];
  for (int j = e0 + w; j < e4; j += 4) {
    int e = order[j];
    int n = (j >= c1) + (j >= c2) + (j >= c3);
    int v = v0 + n;
    float rlo = b2f(r1b[e * 128 + o]);
    float rhi = b2f(r1b[e * 128 + 64 + o]);
    float acc = Ybias[v * 64 + o];
    const u16b* Tp = T + n * 8192 + o;
#pragma unroll
    for (int k = 0; k < 64; ++k)
      acc += rdlane(rlo, k) * b2f(Tp[k * 64]);
#pragma unroll
    for (int k = 0; k < 64; ++k)
      acc += rdlane(rhi, k) * b2f(Tp[(64 + k) * 64]);
    atomicAdd(&agg[dst[e] * 64 + o], acc);
  }
}

// ---------------- GRU cell, in-place on h ----------------
__global__ void k_gru(const float* __restrict__ agg, float* __restrict__ h,
                      const float* __restrict__ WtIH, const float* __restrict__ WtHH,
                      const float* __restrict__ b_ih, const float* __restrict__ b_hh) {
  int v = blockIdx.x, o = threadIdx.x;            // 64 threads = 1 wave
  __shared__ float x[D], hp[D];
  x[o] = fmaxf(agg[v * D + o], 0.f);
  hp[o] = h[v * D + o];
  __syncthreads();
  float gr = b_ih[o],     gz = b_ih[D + o],  gn = b_ih[2 * D + o];
  float hr = b_hh[o],     hz = b_hh[D + o],  hn = b_hh[2 * D + o];
  for (int i = 0; i < D; ++i) {
    float xi = x[i], hi = hp[i];
    const float* wi = WtIH + i * 192;
    const float* wh = WtHH + i * 192;
    gr += wi[o] * xi;       gz += wi[D + o] * xi;       gn += wi[2 * D + o] * xi;
    hr += wh[o] * hi;       hz += wh[D + o] * hi;       hn += wh[2 * D + o] * hi;
  }
  float r = sigf(gr + hr);
  float z = sigf(gz + hz);
  float n = tanhf(gn + r * hn);
  h[v * D + o] = (1.f - z) * n + z * hp[o];
}

// ---------------- Set2Set (6 iters, 3-layer LSTM) + predict head ----------------
__global__ __launch_bounds__(256) void k_s2s(
    const float* __restrict__ h,
    const float* Wih0, const float* Whh0, const float* bih0, const float* bhh0,
    const float* Wih1, const float* Whh1, const float* bih1, const float* bhh1,
    const float* Wih2, const float* Whh2, const float* bih2, const float* bhh2,
    const float* W_p1, const float* b_p1, const float* W_p2, const float* b_p2,
    float* __restrict__ out) {
  int g = blockIdx.x, t = threadIdx.x;            // 256 threads
  __shared__ float hsL[3][D], csL[3][D], q_star[2 * D], gates[4 * D], att[NPG], scal[2];
  const float* hb = h + (size_t)g * NPG * D;
  if (t < D) {
    hsL[0][t] = 0.f; hsL[1][t] = 0.f; hsL[2][t] = 0.f;
    csL[0][t] = 0.f; csL[1][t] = 0.f; csL[2][t] = 0.f;
  }
  if (t < 2 * D) q_star[t] = 0.f;
  __syncthreads();
  for (int it = 0; it < S2S_ITERS; ++it) {
    for (int l = 0; l < 3; ++l) {
      const float* Wih = (l == 0) ? Wih0 : ((l == 1) ? Wih1 : Wih2);
      const float* Whh = (l == 0) ? Whh0 : ((l == 1) ? Whh1 : Whh2);
      const float* bih = (l == 0) ? bih0 : ((l == 1) ? bih1 : bih2);
      const float* bhh = (l == 0) ? bhh0 : ((l == 1) ? bhh1 : bhh2);
      const float* xin = (l == 0) ? q_star : hsL[l - 1];
      int in_dim = (l == 0) ? 2 * D : D;
      float gacc = bih[t] + bhh[t];
      const float* wr = Wih + t * in_dim;
      for (int k = 0; k < in_dim; ++k) gacc += wr[k] * xin[k];
      const float* hr = Whh + t * D;
      const float* hh = hsL[l];
      for (int k = 0; k < D; ++k) gacc += hr[k] * hh[k];
      gates[t] = gacc;
      __syncthreads();
      if (t < D) {
        float ig = gates[t], fg = gates[D + t], gg = gates[2 * D + t], og = gates[3 * D + t];
        float c = sigf(fg) * csL[l][t] + sigf(ig) * tanhf(gg);
        csL[l][t] = c;
        hsL[l][t] = sigf(og) * tanhf(c);
      }
      __syncthreads();
    }
    if (t < NPG) {
      float e = 0.f;
      for (int dd = 0; dd < D; ++dd) e += hb[t * D + dd] * hsL[2][dd];
      att[t] = e;
    }
    __syncthreads();
    if (t == 0) {
      float m = att[0];
      for (int n = 1; n < NPG; ++n) m = fmaxf(m, att[n]);
      scal[0] = m;
    }
    __syncthreads();
    if (t < NPG) att[t] = expf(att[t] - scal[0]);
    __syncthreads();
    if (t == 0) {
      float s = 0.f;
      for (int n = 0; n < NPG; ++n) s += att[n];
      scal[1] = 1.f / s;
    }
    __syncthreads();
    if (t < D) {
      float inv = scal[1];
      float r = 0.f;
      for (int n = 0; n < NPG; ++n) r += hb[n * D + t] * att[n];
      q_star[t] = hsL[2][t];
      q_star[D + t] = r * inv;
    }
    __syncthreads();
  }
  if (t < D) {
    float p = b_p1[t];
    for (int k = 0; k < 2 * D; ++k) p += q_star[k] * W_p1[k * D + t];
    p = fmaxf(p, 0.f);
    att[t] = p * W_p2[t];
  }
  __syncthreads();
  if (t == 0) {
    float s = 0.f;
    for (int j = 0; j < D; ++j) s += att[j];
    out[g] = s + b_p2[0];
  }
}

extern "C" void kernel_launch(void* const* d_in, const int* in_sizes, int n_in,
                              void* d_out, int out_size, void* d_ws, size_t ws_size,
                              hipStream_t stream) {
  const float* node_feats = (const float*)d_in[0];
  const float* edge_feats = (const float*)d_in[1];
  const int*   src        = (const int*)d_in[2];
  const int*   dst        = (const int*)d_in[3];
  // d_in[4] graph_ids: contiguous 100-node segments by construction
  const float* W_proj = (const float*)d_in[5];
  const float* b_proj = (const float*)d_in[6];
  const float* W_e1   = (const float*)d_in[7];
  const float* b_e1   = (const float*)d_in[8];
  const float* W_e2   = (const float*)d_in[9];
  const float* b_e2   = (const float*)d_in[10];
  const float* b_conv = (const float*)d_in[11];
  const float* W_ih   = (const float*)d_in[12];
  const float* W_hh   = (const float*)d_in[13];
  const float* b_ih   = (const float*)d_in[14];
  const float* b_hh   = (const float*)d_in[15];
  const float* Wih0 = (const float*)d_in[16]; const float* Whh0 = (const float*)d_in[17];
  const float* bih0 = (const float*)d_in[18]; const float* bhh0 = (const float*)d_in[19];
  const float* Wih1 = (const float*)d_in[20]; const float* Whh1 = (const float*)d_in[21];
  const float* bih1 = (const float*)d_in[22]; const float* bhh1 = (const float*)d_in[23];
  const float* Wih2 = (const float*)d_in[24]; const float* Whh2 = (const float*)d_in[25];
  const float* bih2 = (const float*)d_in[26]; const float* bhh2 = (const float*)d_in[27];
  const float* W_p1 = (const float*)d_in[28]; const float* b_p1 = (const float*)d_in[29];
  const float* W_p2 = (const float*)d_in[30]; const float* b_p2 = (const float*)d_in[31];

  // ---- workspace layout (total ~14.7 MB) ----
  char* ws = (char*)d_ws;
  float* h      = (float*)(ws + 0);               // 1,024,000
  float* agg    = (float*)(ws + 1024000);         // 1,024,000
  u16b*  r1b    = (u16b*) (ws + 2048000);         // 10,240,000
  float* Ybias  = (float*)(ws + 12288000);        // 1,024,000
  float* WtIH   = (float*)(ws + 13312000);        // 49,152
  float* WtHH   = (float*)(ws + 13361152);        // 49,152
  int*   offs   = (int*)  (ws + 13410304);        // 16,384 (4096 bins)
  int*   cursor = (int*)  (ws + 13426688);        // 16,384
  int*   order  = (int*)  (ws + 13443072);        // 160,000
  u16b*  W2b    = (u16b*) (ws + 13603072);        // 1,048,576 -> end 14,651,648

  k_proj<<<V_N, 64, 0, stream>>>(node_feats, W_proj, b_proj, h);
  k_prep<<<2048, 256, 0, stream>>>(W_ih, W_hh, W_e2, WtIH, WtHH, W2b);
  k_edge1<<<E_N / 8, 128, 0, stream>>>(edge_feats, W_e1, b_e1, r1b);
  // counting sort by src (uses cursor as counts first)
  k_zero<<<16, 256, 0, stream>>>(cursor);
  k_hist<<<(E_N + 255) / 256, 256, 0, stream>>>(src, cursor);
  k_scan<<<1, 256, 0, stream>>>(cursor, offs, cursor);
  k_scatter<<<(E_N + 255) / 256, 256, 0, stream>>>(src, cursor, order);

  for (int s = 0; s < NSTEPS; ++s) {
    k_ybias<<<V_N, 64, 0, stream>>>(h, b_e2, Ybias);
    k_init_agg<<<(V_N * D) / 256, 256, 0, stream>>>(agg, b_conv);
    k_msg4<<<V_N / 4, 256, 0, stream>>>(h, r1b, (const uint4*)W2b, Ybias,
                                        offs, order, dst, agg);
    k_gru<<<V_N, 64, 0, stream>>>(agg, h, WtIH, WtHH, b_ih, b_hh);
  }
  k_s2s<<<G_N, 256, 0, stream>>>(h,
      Wih0, Whh0, bih0, bhh0, Wih1, Whh1, bih1, bhh1, Wih2, Whh2, bih2, bhh2,
      W_p1, b_p1, W_p2, b_p2, (float*)d_out);
}

// Round 7
// 961.124 us; speedup vs baseline: 3.5120x; 1.1714x over previous
//
#include <hip/hip_runtime.h>
#include <hip/hip_bf16.h>
#include <cstdint>
#include <cstddef>

#define D 64
#define V_N 4000
#define E_N 40000
#define G_N 40
#define NPG 100          // nodes per graph (contiguous)
#define NODE_IN 74
#define EDGE_IN 128
#define NSTEPS 6
#define S2S_ITERS 6

typedef unsigned short u16b;
typedef __attribute__((ext_vector_type(8))) short bf16x8;
typedef __attribute__((ext_vector_type(4))) float f32x4;

__device__ __forceinline__ float b2f(u16b u) {
  union { unsigned int i; float f; } v; v.i = ((unsigned int)u) << 16; return v.f;
}
__device__ __forceinline__ u16b f2b(float f) {
  union { unsigned int i; float f; } v; v.f = f;
  unsigned int r = (v.i + 0x7fffu + ((v.i >> 16) & 1u)) >> 16;
  return (u16b)r;
}
__device__ __forceinline__ float sigf(float x) { return 1.f / (1.f + expf(-x)); }
__device__ __forceinline__ float rdlane(float v, int l) {
  return __int_as_float(__builtin_amdgcn_readlane(__float_as_int(v), l));
}

// ---------------- h = relu(node_feats @ W_proj + b_proj) ----------------
__global__ void k_proj(const float* __restrict__ nf, const float* __restrict__ W,
                       const float* __restrict__ b, float* __restrict__ h) {
  int v = blockIdx.x, o = threadIdx.x;            // 64 threads
  const float* row = nf + v * NODE_IN;
  float acc = b[o];
  for (int i = 0; i < NODE_IN; ++i)
    acc += row[i] * W[i * D + o];
  h[v * D + o] = fmaxf(acc, 0.f);
}

// ------- prep: GRU transpose + W2 MFMA-fragment swizzle + LSTM WT + bsum ----
// W2s layout (u16 units): idx = t16*1024 + kb*512 + lane*8 + j, where
//   m15 = lane&15, quad = lane>>4, m_idx = t16*16+m15 (= k*64+o), i = kb*32+quad*8+j
//   source: W_e2[k*4096 + i*64 + o]
__global__ void k_prep(const float* __restrict__ W_ih, const float* __restrict__ W_hh,
                       const float* __restrict__ W_e2,
                       const float* __restrict__ Wih0, const float* __restrict__ Whh0,
                       const float* __restrict__ bih0, const float* __restrict__ bhh0,
                       const float* __restrict__ Wih1, const float* __restrict__ Whh1,
                       const float* __restrict__ bih1, const float* __restrict__ bhh1,
                       const float* __restrict__ Wih2, const float* __restrict__ Whh2,
                       const float* __restrict__ bih2, const float* __restrict__ bhh2,
                       float* __restrict__ WtIH, float* __restrict__ WtHH,
                       u16b* __restrict__ W2s,
                       float* __restrict__ WT0, float* __restrict__ WT1,
                       float* __restrict__ WT2, float* __restrict__ bsum) {
  int idx = blockIdx.x * 256 + threadIdx.x;       // grid covers 524288
  if (idx < 192 * 64) {
    int j = idx >> 6, i = idx & 63;
    WtIH[i * 192 + j] = W_ih[j * 64 + i];
    WtHH[i * 192 + j] = W_hh[j * 64 + i];
  }
  if (idx < 524288) {
    int t16 = idx >> 10, rem = idx & 1023;
    int kb = rem >> 9, rem2 = rem & 511;
    int lane = rem2 >> 3, j = rem2 & 7;
    int m15 = lane & 15, quad = lane >> 4;
    int m_idx = t16 * 16 + m15;
    int k = m_idx >> 6, o = m_idx & 63;
    int i = kb * 32 + quad * 8 + j;
    W2s[idx] = f2b(W_e2[k * 4096 + i * 64 + o]);
  }
  if (idx < 49152) {                              // WT0: [k][gate], k<192
    int k = idx >> 8, t = idx & 255;
    WT0[idx] = (k < 128) ? Wih0[t * 128 + k] : Whh0[t * 64 + (k - 128)];
  }
  if (idx < 32768) {                              // WT1/WT2: [k][gate], k<128
    int k = idx >> 8, t = idx & 255;
    WT1[idx] = (k < 64) ? Wih1[t * 64 + k] : Whh1[t * 64 + (k - 64)];
    WT2[idx] = (k < 64) ? Wih2[t * 64 + k] : Whh2[t * 64 + (k - 64)];
  }
  if (idx < 256) bsum[idx] = bih0[idx] + bhh0[idx];
  else if (idx < 512) bsum[idx] = bih1[idx - 256] + bhh1[idx - 256];
  else if (idx < 768) bsum[idx] = bih2[idx - 512] + bhh2[idx - 512];
}

// ---------------- r1 = relu(edge_feats @ W_e1 + b_e1) -> bf16 ----------------
__global__ void k_edge1(const float* __restrict__ ef, const float* __restrict__ W,
                        const float* __restrict__ b, u16b* __restrict__ r1b) {
  __shared__ float x[8][EDGE_IN];
  int t = threadIdx.x;                            // 128 threads
  int e0 = blockIdx.x * 8;
  for (int e = 0; e < 8; ++e)
    x[e][t] = ef[(e0 + e) * EDGE_IN + t];
  __syncthreads();
  float acc[8];
  float bb = b[t];
#pragma unroll
  for (int e = 0; e < 8; ++e) acc[e] = bb;
  for (int i = 0; i < EDGE_IN; ++i) {
    float w = W[i * 128 + t];
#pragma unroll
    for (int e = 0; e < 8; ++e) acc[e] += x[e][i] * w;
  }
  for (int e = 0; e < 8; ++e)
    r1b[(e0 + e) * 128 + t] = f2b(fmaxf(acc[e], 0.f));
}

// ---------------- counting sort of edges by src ----------------
__global__ void k_zero(int* __restrict__ cnt) {   // 4096 bins
  cnt[blockIdx.x * 256 + threadIdx.x] = 0;
}
__global__ void k_hist(const int* __restrict__ src, int* __restrict__ cnt) {
  int e = blockIdx.x * 256 + threadIdx.x;
  if (e < E_N) atomicAdd(&cnt[src[e]], 1);
}
__global__ __launch_bounds__(256) void k_scan(const int* __restrict__ cnt,
                                              int* __restrict__ offs,
                                              int* __restrict__ cursor) {
  __shared__ int part[256];
  int t = threadIdx.x;                            // single block
  int local[16], s = 0;
#pragma unroll
  for (int b = 0; b < 16; ++b) { local[b] = cnt[t * 16 + b]; s += local[b]; }
  part[t] = s;
  __syncthreads();
  for (int off = 1; off < 256; off <<= 1) {
    int v = (t >= off) ? part[t - off] : 0;
    __syncthreads();
    part[t] += v;
    __syncthreads();
  }
  int run = part[t] - s;                          // exclusive base
#pragma unroll
  for (int b = 0; b < 16; ++b) {
    offs[t * 16 + b] = run;
    cursor[t * 16 + b] = run;
    run += local[b];
  }
}
__global__ void k_scatter(const int* __restrict__ src, int* __restrict__ cursor,
                          int* __restrict__ order) {
  int e = blockIdx.x * 256 + threadIdx.x;
  if (e < E_N) {
    int pos = atomicAdd(&cursor[src[e]], 1);
    order[pos] = e;
  }
}

// ---------------- agg init: agg[v][o] = b_conv[o] ----------------
__global__ void k_init_agg(float* __restrict__ agg, const float* __restrict__ b_conv) {
  int idx = blockIdx.x * 256 + threadIdx.x;
  agg[idx] = b_conv[idx & 63];
}

// ------ block = 4 src nodes. Phase A: T[n][k*64+o] via MFMA 16x16x32 bf16
// ------ (A = swizzled W2 fragments, B = h columns). Phase B: per-edge dot.
__global__ __launch_bounds__(256) void k_msg5(
    const float* __restrict__ h, const u16b* __restrict__ r1b,
    const u16b* __restrict__ W2s, const float* __restrict__ b_e2,
    const int* __restrict__ offs, const int* __restrict__ order,
    const int* __restrict__ dst, float* __restrict__ agg) {
  __shared__ __align__(16) u16b T[4 * 8192];      // 64 KB exactly
  int t = threadIdx.x;
  int v0 = blockIdx.x * 4;
  int w = t >> 6, lane = t & 63;
  int n15 = lane & 15, quad = lane >> 4;

  // Ybias for my wave's node, per-lane o=lane (b_e2 reads coalesced, L1-hot)
  float ybreg = 0.f;
  {
    const float* hv = h + (v0 + w) * 64;
#pragma unroll 8
    for (int i = 0; i < 64; ++i)
      ybreg += hv[i] * b_e2[i * 64 + lane];
  }

  // B fragments: B[i = kb*32 + quad*8 + j][n = n15] = h[v0+n][i], zero for n>=4
  bf16x8 bfrag[2];
  {
    union { bf16x8 v; u16b s[8]; } bu0, bu1;
#pragma unroll
    for (int j = 0; j < 8; ++j) { bu0.s[j] = 0; bu1.s[j] = 0; }
    if (n15 < 4) {
      const float* hp = h + (v0 + n15) * 64 + quad * 8;
#pragma unroll
      for (int j = 0; j < 8; ++j) {
        bu0.s[j] = f2b(hp[j]);
        bu1.s[j] = f2b(hp[32 + j]);
      }
    }
    bfrag[0] = bu0.v; bfrag[1] = bu1.v;
  }

  // Phase A: wave w owns m-tiles t16 = w*128 .. w*128+127
  const uint4* W4 = (const uint4*)W2s;
#pragma unroll 4
  for (int tt = 0; tt < 128; ++tt) {
    int t16 = w * 128 + tt;
    uint4 a0 = W4[t16 * 128 + lane];              // kb=0 fragment (16B/lane)
    uint4 a1 = W4[t16 * 128 + 64 + lane];         // kb=1 fragment
    f32x4 acc = {0.f, 0.f, 0.f, 0.f};
    union { uint4 u; bf16x8 v; } c0, c1;
    c0.u = a0; c1.u = a1;
    acc = __builtin_amdgcn_mfma_f32_16x16x32_bf16(c0.v, bfrag[0], acc, 0, 0, 0);
    acc = __builtin_amdgcn_mfma_f32_16x16x32_bf16(c1.v, bfrag[1], acc, 0, 0, 0);
    if (n15 < 4) {                                // D[row=quad*4+r][col=n15]
      uint2 pk;
      pk.x = (unsigned)f2b(acc[0]) | ((unsigned)f2b(acc[1]) << 16);
      pk.y = (unsigned)f2b(acc[2]) | ((unsigned)f2b(acc[3]) << 16);
      *(uint2*)&T[n15 * 8192 + t16 * 16 + quad * 4] = pk;
    }
  }
  __syncthreads();

  // Phase B: wave w handles node v0+w's edges
  int v = v0 + w;
  int e0 = offs[v], e1 = offs[v + 1];
  const u16b* Tp = T + w * 8192 + lane;
  for (int j = e0; j < e1; ++j) {
    int e = order[j];
    float rlo = b2f(r1b[e * 128 + lane]);
    float rhi = b2f(r1b[e * 128 + 64 + lane]);
    float acc = ybreg;
#pragma unroll
    for (int k = 0; k < 64; ++k)
      acc += rdlane(rlo, k) * b2f(Tp[k * 64]);
#pragma unroll
    for (int k = 0; k < 64; ++k)
      acc += rdlane(rhi, k) * b2f(Tp[(64 + k) * 64]);
    atomicAdd(&agg[dst[e] * 64 + lane], acc);
  }
}

// ---------------- GRU cell, 4 nodes/block, in-place on h ----------------
__global__ __launch_bounds__(256) void k_gru(
    const float* __restrict__ agg, float* __restrict__ h,
    const float* __restrict__ WtIH, const float* __restrict__ WtHH,
    const float* __restrict__ b_ih, const float* __restrict__ b_hh) {
  int t = threadIdx.x;
  int n = t >> 6, o = t & 63;
  int v = blockIdx.x * 4 + n;
  __shared__ float x[4][D], hp[4][D];
  x[n][o] = fmaxf(agg[v * D + o], 0.f);
  hp[n][o] = h[v * D + o];
  __syncthreads();
  float gr = b_ih[o],     gz = b_ih[D + o],  gn = b_ih[2 * D + o];
  float hr = b_hh[o],     hz = b_hh[D + o],  hn = b_hh[2 * D + o];
  for (int i = 0; i < D; ++i) {
    float xi = x[n][i], hi = hp[n][i];
    const float* wi = WtIH + i * 192;
    const float* wh = WtHH + i * 192;
    gr += wi[o] * xi;       gz += wi[D + o] * xi;       gn += wi[2 * D + o] * xi;
    hr += wh[o] * hi;       hz += wh[D + o] * hi;       hn += wh[2 * D + o] * hi;
  }
  float r = sigf(gr + hr);
  float z = sigf(gz + hz);
  float nn = tanhf(gn + r * hn);
  h[v * D + o] = (1.f - z) * nn + z * hp[n][o];
}

// ---------------- Set2Set (6 iters, 3-layer LSTM) + predict head ----------------
__global__ __launch_bounds__(256) void k_s2s(
    const float* __restrict__ h,
    const float* __restrict__ WT0, const float* __restrict__ WT1,
    const float* __restrict__ WT2, const float* __restrict__ bsum,
    const float* __restrict__ W_p1, const float* __restrict__ b_p1,
    const float* __restrict__ W_p2, const float* __restrict__ b_p2,
    float* __restrict__ out) {
  int g = blockIdx.x, t = threadIdx.x;            // 256 threads
  __shared__ float hL[NPG * 65];                  // padded graph h-block
  __shared__ float hsL[3][D], csL[3][D], q_star[2 * D], xc[192], gates[256],
                   att[NPG], scal[2];
  // stage this graph's 100x64 h rows (pad stride 65 to break bank conflicts)
  for (int idx = t; idx < NPG * 64; idx += 256)
    hL[(idx >> 6) * 65 + (idx & 63)] = h[(size_t)g * NPG * 64 + idx];
  if (t < D) {
    hsL[0][t] = 0.f; hsL[1][t] = 0.f; hsL[2][t] = 0.f;
    csL[0][t] = 0.f; csL[1][t] = 0.f; csL[2][t] = 0.f;
  }
  if (t < 2 * D) q_star[t] = 0.f;
  __syncthreads();
  for (int it = 0; it < S2S_ITERS; ++it) {
    // ---- layer 0 (in_dim 128 + hidden 64 = 192) ----
    if (t < 128) xc[t] = q_star[t];
    if (t < 64) xc[128 + t] = hsL[0][t];
    __syncthreads();
    {
      float gacc = bsum[t];
#pragma unroll 16
      for (int k = 0; k < 192; ++k) gacc += WT0[k * 256 + t] * xc[k];
      gates[t] = gacc;
    }
    __syncthreads();
    if (t < 64) {
      float c = sigf(gates[64 + t]) * csL[0][t] + sigf(gates[t]) * tanhf(gates[128 + t]);
      csL[0][t] = c;
      hsL[0][t] = sigf(gates[192 + t]) * tanhf(c);
    }
    __syncthreads();
    // ---- layers 1,2 (64 + 64 = 128) ----
    for (int l = 1; l < 3; ++l) {
      const float* WT = (l == 1) ? WT1 : WT2;
      if (t < 64) { xc[t] = hsL[l - 1][t]; xc[64 + t] = hsL[l][t]; }
      __syncthreads();
      float gacc = bsum[l * 256 + t];
#pragma unroll 16
      for (int k = 0; k < 128; ++k) gacc += WT[k * 256 + t] * xc[k];
      gates[t] = gacc;
      __syncthreads();
      if (t < 64) {
        float c = sigf(gates[64 + t]) * csL[l][t] + sigf(gates[t]) * tanhf(gates[128 + t]);
        csL[l][t] = c;
        hsL[l][t] = sigf(gates[192 + t]) * tanhf(c);
      }
      __syncthreads();
    }
    // ---- attention over the graph's 100 nodes ----
    if (t < NPG) {
      float e = 0.f;
#pragma unroll 8
      for (int dd = 0; dd < D; ++dd) e += hL[t * 65 + dd] * hsL[2][dd];
      att[t] = e;
    }
    __syncthreads();
    if (t == 0) {
      float m = att[0];
      for (int n = 1; n < NPG; ++n) m = fmaxf(m, att[n]);
      scal[0] = m;
    }
    __syncthreads();
    if (t < NPG) att[t] = expf(att[t] - scal[0]);
    __syncthreads();
    if (t == 0) {
      float s = 0.f;
      for (int n = 0; n < NPG; ++n) s += att[n];
      scal[1] = 1.f / s;
    }
    __syncthreads();
    if (t < D) {
      float r = 0.f;
#pragma unroll 4
      for (int n = 0; n < NPG; ++n) r += hL[n * 65 + t] * att[n];
      q_star[t] = hsL[2][t];
      q_star[D + t] = r * scal[1];
    }
    __syncthreads();
  }
  // predict: relu(q_star @ W_p1 + b_p1) @ W_p2 + b_p2
  if (t < D) {
    float p = b_p1[t];
    for (int k = 0; k < 2 * D; ++k) p += q_star[k] * W_p1[k * D + t];
    p = fmaxf(p, 0.f);
    att[t] = p * W_p2[t];
  }
  __syncthreads();
  if (t == 0) {
    float s = 0.f;
    for (int j = 0; j < D; ++j) s += att[j];
    out[g] = s + b_p2[0];
  }
}

extern "C" void kernel_launch(void* const* d_in, const int* in_sizes, int n_in,
                              void* d_out, int out_size, void* d_ws, size_t ws_size,
                              hipStream_t stream) {
  const float* node_feats = (const float*)d_in[0];
  const float* edge_feats = (const float*)d_in[1];
  const int*   src        = (const int*)d_in[2];
  const int*   dst        = (const int*)d_in[3];
  // d_in[4] graph_ids: contiguous 100-node segments by construction
  const float* W_proj = (const float*)d_in[5];
  const float* b_proj = (const float*)d_in[6];
  const float* W_e1   = (const float*)d_in[7];
  const float* b_e1   = (const float*)d_in[8];
  const float* W_e2   = (const float*)d_in[9];
  const float* b_e2   = (const float*)d_in[10];
  const float* b_conv = (const float*)d_in[11];
  const float* W_ih   = (const float*)d_in[12];
  const float* W_hh   = (const float*)d_in[13];
  const float* b_ih   = (const float*)d_in[14];
  const float* b_hh   = (const float*)d_in[15];
  const float* Wih0 = (const float*)d_in[16]; const float* Whh0 = (const float*)d_in[17];
  const float* bih0 = (const float*)d_in[18]; const float* bhh0 = (const float*)d_in[19];
  const float* Wih1 = (const float*)d_in[20]; const float* Whh1 = (const float*)d_in[21];
  const float* bih1 = (const float*)d_in[22]; const float* bhh1 = (const float*)d_in[23];
  const float* Wih2 = (const float*)d_in[24]; const float* Whh2 = (const float*)d_in[25];
  const float* bih2 = (const float*)d_in[26]; const float* bhh2 = (const float*)d_in[27];
  const float* W_p1 = (const float*)d_in[28]; const float* b_p1 = (const float*)d_in[29];
  const float* W_p2 = (const float*)d_in[30]; const float* b_p2 = (const float*)d_in[31];

  // ---- workspace layout (total ~14.1 MB, all 16B-aligned) ----
  char* ws = (char*)d_ws;
  float* h      = (float*)(ws + 0);               // 1,024,000
  float* agg    = (float*)(ws + 1024000);         // 1,024,000
  u16b*  r1b    = (u16b*) (ws + 2048000);         // 10,240,000
  float* WtIH   = (float*)(ws + 12288000);        // 49,152
  float* WtHH   = (float*)(ws + 12337152);        // 49,152
  int*   offs   = (int*)  (ws + 12386304);        // 16,384 (4096 bins)
  int*   cursor = (int*)  (ws + 12402688);        // 16,384
  int*   order  = (int*)  (ws + 12419072);        // 160,000
  u16b*  W2s    = (u16b*) (ws + 12579072);        // 1,048,576 (MFMA-swizzled)
  float* WT0    = (float*)(ws + 13627648);        // 196,608
  float* WT1    = (float*)(ws + 13824256);        // 131,072
  float* WT2    = (float*)(ws + 13955328);        // 131,072
  float* bsum   = (float*)(ws + 14086400);        // 3,072 -> end 14,089,472

  k_proj<<<V_N, 64, 0, stream>>>(node_feats, W_proj, b_proj, h);
  k_prep<<<2048, 256, 0, stream>>>(W_ih, W_hh, W_e2,
      Wih0, Whh0, bih0, bhh0, Wih1, Whh1, bih1, bhh1, Wih2, Whh2, bih2, bhh2,
      WtIH, WtHH, W2s, WT0, WT1, WT2, bsum);
  k_edge1<<<E_N / 8, 128, 0, stream>>>(edge_feats, W_e1, b_e1, r1b);
  // counting sort by src (uses cursor as counts first)
  k_zero<<<16, 256, 0, stream>>>(cursor);
  k_hist<<<(E_N + 255) / 256, 256, 0, stream>>>(src, cursor);
  k_scan<<<1, 256, 0, stream>>>(cursor, offs, cursor);
  k_scatter<<<(E_N + 255) / 256, 256, 0, stream>>>(src, cursor, order);

  for (int s = 0; s < NSTEPS; ++s) {
    k_init_agg<<<(V_N * D) / 256, 256, 0, stream>>>(agg, b_conv);
    k_msg5<<<V_N / 4, 256, 0, stream>>>(h, r1b, W2s, b_e2, offs, order, dst, agg);
    k_gru<<<V_N / 4, 256, 0, stream>>>(agg, h, WtIH, WtHH, b_ih, b_hh);
  }
  k_s2s<<<G_N, 256, 0, stream>>>(h, WT0, WT1, WT2, bsum,
      W_p1, b_p1, W_p2, b_p2, (float*)d_out);
}

// Round 8
// 697.469 us; speedup vs baseline: 4.8396x; 1.3780x over previous
//
#include <hip/hip_runtime.h>
#include <hip/hip_bf16.h>
#include <cstdint>
#include <cstddef>

#define D 64
#define V_N 4000
#define E_N 40000
#define G_N 40
#define NPG 100          // nodes per graph (contiguous)
#define NODE_IN 74
#define EDGE_IN 128
#define NSTEPS 6
#define S2S_ITERS 6

typedef unsigned short u16b;
typedef __attribute__((ext_vector_type(8))) short bf16x8;
typedef __attribute__((ext_vector_type(4))) float f32x4;

__device__ __forceinline__ float b2f(u16b u) {
  union { unsigned int i; float f; } v; v.i = ((unsigned int)u) << 16; return v.f;
}
__device__ __forceinline__ u16b f2b(float f) {
  union { unsigned int i; float f; } v; v.f = f;
  unsigned int r = (v.i + 0x7fffu + ((v.i >> 16) & 1u)) >> 16;
  return (u16b)r;
}
__device__ __forceinline__ float sigf(float x) { return 1.f / (1.f + expf(-x)); }

// ---------------- h = relu(node_feats @ W_proj + b_proj) ----------------
__global__ void k_proj(const float* __restrict__ nf, const float* __restrict__ W,
                       const float* __restrict__ b, float* __restrict__ h) {
  int v = blockIdx.x, o = threadIdx.x;            // 64 threads
  const float* row = nf + v * NODE_IN;
  float acc = b[o];
  for (int i = 0; i < NODE_IN; ++i)
    acc += row[i] * W[i * D + o];
  h[v * D + o] = fmaxf(acc, 0.f);
}

// ------- prep: GRU transpose + W2 fragment permutation + LSTM WT + bsum ----
// W2s: 4 o-quarters x 2048 m-rows x 64 i.  A-fragment flat layout:
//   idx = q*131072 + t16*1024 + kbA*512 + lane*8 + jA
//   m_idx = t16*16 + (lane&15), i = kbA*32 + (lane>>4)*8 + jA
//   m_idx -> (k,o): kb=m_idx>>9, quadB=(m_idx>>7)&3, n15B=(m_idx>>3)&15, j=m_idx&7
//   k = kb*32+quadB*8+j,  o = q*16+n15B   (so Phase-A D-tiles land in
//   B-fragment order for Phase B)
__global__ void k_prep(const float* __restrict__ W_ih, const float* __restrict__ W_hh,
                       const float* __restrict__ W_e2,
                       const float* __restrict__ Wih0, const float* __restrict__ Whh0,
                       const float* __restrict__ bih0, const float* __restrict__ bhh0,
                       const float* __restrict__ Wih1, const float* __restrict__ Whh1,
                       const float* __restrict__ bih1, const float* __restrict__ bhh1,
                       const float* __restrict__ Wih2, const float* __restrict__ Whh2,
                       const float* __restrict__ bih2, const float* __restrict__ bhh2,
                       float* __restrict__ WtIH, float* __restrict__ WtHH,
                       u16b* __restrict__ W2s,
                       float* __restrict__ WT0, float* __restrict__ WT1,
                       float* __restrict__ WT2, float* __restrict__ bsum) {
  int idx = blockIdx.x * 256 + threadIdx.x;       // grid covers 524288
  if (idx < 192 * 64) {
    int j = idx >> 6, i = idx & 63;
    WtIH[i * 192 + j] = W_ih[j * 64 + i];
    WtHH[i * 192 + j] = W_hh[j * 64 + i];
  }
  if (idx < 524288) {
    int q = idx >> 17, rem = idx & 131071;
    int t16 = rem >> 10, rem2 = rem & 1023;
    int kbA = rem2 >> 9, rem3 = rem2 & 511;
    int lane = rem3 >> 3, jA = rem3 & 7;
    int m15 = lane & 15, quadA = lane >> 4;
    int m_idx = t16 * 16 + m15;
    int i = kbA * 32 + quadA * 8 + jA;
    int kb = m_idx >> 9, quadB = (m_idx >> 7) & 3;
    int n15B = (m_idx >> 3) & 15, j = m_idx & 7;
    int k = kb * 32 + quadB * 8 + j;
    int o = q * 16 + n15B;
    W2s[idx] = f2b(W_e2[k * 4096 + i * 64 + o]);
  }
  if (idx < 49152) {                              // WT0: [k][gate], k<192
    int k = idx >> 8, t = idx & 255;
    WT0[idx] = (k < 128) ? Wih0[t * 128 + k] : Whh0[t * 64 + (k - 128)];
  }
  if (idx < 32768) {                              // WT1/WT2: [k][gate], k<128
    int k = idx >> 8, t = idx & 255;
    WT1[idx] = (k < 64) ? Wih1[t * 64 + k] : Whh1[t * 64 + (k - 64)];
    WT2[idx] = (k < 64) ? Wih2[t * 64 + k] : Whh2[t * 64 + (k - 64)];
  }
  if (idx < 256) bsum[idx] = bih0[idx] + bhh0[idx];
  else if (idx < 512) bsum[idx] = bih1[idx - 256] + bhh1[idx - 256];
  else if (idx < 768) bsum[idx] = bih2[idx - 512] + bhh2[idx - 512];
}

// ---------------- r1 = relu(edge_feats @ W_e1 + b_e1) -> bf16 ----------------
__global__ void k_edge1(const float* __restrict__ ef, const float* __restrict__ W,
                        const float* __restrict__ b, u16b* __restrict__ r1b) {
  __shared__ float x[8][EDGE_IN];
  int t = threadIdx.x;                            // 128 threads
  int e0 = blockIdx.x * 8;
  for (int e = 0; e < 8; ++e)
    x[e][t] = ef[(e0 + e) * EDGE_IN + t];
  __syncthreads();
  float acc[8];
  float bb = b[t];
#pragma unroll
  for (int e = 0; e < 8; ++e) acc[e] = bb;
  for (int i = 0; i < EDGE_IN; ++i) {
    float w = W[i * 128 + t];
#pragma unroll
    for (int e = 0; e < 8; ++e) acc[e] += x[e][i] * w;
  }
  for (int e = 0; e < 8; ++e)
    r1b[(e0 + e) * 128 + t] = f2b(fmaxf(acc[e], 0.f));
}

// ---------------- counting sort of edges by src ----------------
__global__ void k_zero(int* __restrict__ cnt) {   // 4096 bins
  cnt[blockIdx.x * 256 + threadIdx.x] = 0;
}
__global__ void k_hist(const int* __restrict__ src, int* __restrict__ cnt) {
  int e = blockIdx.x * 256 + threadIdx.x;
  if (e < E_N) atomicAdd(&cnt[src[e]], 1);
}
__global__ __launch_bounds__(256) void k_scan(const int* __restrict__ cnt,
                                              int* __restrict__ offs,
                                              int* __restrict__ cursor) {
  __shared__ int part[256];
  int t = threadIdx.x;                            // single block
  int local[16], s = 0;
#pragma unroll
  for (int b = 0; b < 16; ++b) { local[b] = cnt[t * 16 + b]; s += local[b]; }
  part[t] = s;
  __syncthreads();
  for (int off = 1; off < 256; off <<= 1) {
    int v = (t >= off) ? part[t - off] : 0;
    __syncthreads();
    part[t] += v;
    __syncthreads();
  }
  int run = part[t] - s;                          // exclusive base
#pragma unroll
  for (int b = 0; b < 16; ++b) {
    offs[t * 16 + b] = run;
    cursor[t * 16 + b] = run;
    run += local[b];
  }
}
__global__ void k_scatter(const int* __restrict__ src, int* __restrict__ cursor,
                          int* __restrict__ order) {
  int e = blockIdx.x * 256 + threadIdx.x;
  if (e < E_N) {
    int pos = atomicAdd(&cursor[src[e]], 1);
    order[pos] = e;
  }
}

// ---------------- Ybias[v][o] = sum_i h[v][i] * b_e2[i*64+o] (bf16) ---------
__global__ void k_ybias(const float* __restrict__ h, const float* __restrict__ b_e2,
                        u16b* __restrict__ Yb) {
  int v = blockIdx.x, o = threadIdx.x;            // 64 threads
  float acc = 0.f;
  for (int i = 0; i < D; ++i)
    acc += h[v * D + i] * b_e2[i * 64 + o];
  Yb[v * D + o] = f2b(acc);
}

// ---------------- agg init: agg[v][o] = b_conv[o] ----------------
__global__ void k_init_agg(float* __restrict__ agg, const float* __restrict__ b_conv) {
  int idx = blockIdx.x * 256 + threadIdx.x;
  agg[idx] = b_conv[idx & 63];
}

// ------ block = 16 nodes x 1 o-quarter. Phase A: T[16n][128k][16o] via MFMA
// ------ (full N=16). Phase B: per-node edge-tile MFMA, b128 B-frag reads.
__global__ __launch_bounds__(256) void k_msg6(
    const float* __restrict__ h, const u16b* __restrict__ r1b,
    const u16b* __restrict__ W2s, const u16b* __restrict__ Ybias_b,
    const int* __restrict__ offs, const int* __restrict__ order,
    const int* __restrict__ dst, float* __restrict__ agg) {
  __shared__ __align__(16) u16b TB[16 * 2048];    // 64 KB exactly
  int t = threadIdx.x;
  int g = blockIdx.x >> 2, q = blockIdx.x & 3;
  int v0 = g * 16;
  int w = t >> 6, lane = t & 63;
  int n15 = lane & 15, quad = lane >> 4;

  // ---- Phase A: B-fragments from h (node = n15, i = quad*8+j (+32*kbA)) ----
  bf16x8 hb[2];
  {
    union { bf16x8 v; u16b s[8]; } b0, b1;
    const float* hp = h + (v0 + n15) * 64 + quad * 8;
#pragma unroll
    for (int j = 0; j < 8; ++j) { b0.s[j] = f2b(hp[j]); b1.s[j] = f2b(hp[32 + j]); }
    hb[0] = b0.v; hb[1] = b1.v;
  }
  const uint4* W4 = (const uint4*)(W2s) + (size_t)q * 16384;
#pragma unroll 4
  for (int tt = 0; tt < 32; ++tt) {
    int t16 = w * 32 + tt;
    uint4 a0 = W4[t16 * 128 + lane];
    uint4 a1 = W4[t16 * 128 + 64 + lane];
    union { uint4 u; bf16x8 v; } c0, c1;
    c0.u = a0; c1.u = a1;
    f32x4 acc = {0.f, 0.f, 0.f, 0.f};
    acc = __builtin_amdgcn_mfma_f32_16x16x32_bf16(c0.v, hb[0], acc, 0, 0, 0);
    acc = __builtin_amdgcn_mfma_f32_16x16x32_bf16(c1.v, hb[1], acc, 0, 0, 0);
    // D[row = quad*4+r][col = node n15] -> TB[n15][m_row], +n15*8 rotation
    int flat = (t16 * 16 + quad * 4 + n15 * 8) & 2047;
    uint2 pk;
    pk.x = (unsigned)f2b(acc[0]) | ((unsigned)f2b(acc[1]) << 16);
    pk.y = (unsigned)f2b(acc[2]) | ((unsigned)f2b(acc[3]) << 16);
    *(uint2*)&TB[n15 * 2048 + flat] = pk;
  }
  __syncthreads();

  // ---- Phase B: wave w handles nodes w*4 .. w*4+3 ----
  for (int ni = 0; ni < 4; ++ni) {
    int n = w * 4 + ni;
    int v = v0 + n;
    int e0 = offs[v], e1 = offs[v + 1];
    if (e0 >= e1) continue;
    bf16x8 bfr[4];                                // B-frags: one b128 each
#pragma unroll
    for (int kb = 0; kb < 4; ++kb) {
      int flat = (((kb * 64 + quad * 16 + n15) << 3) + n * 8) & 2047;
      bfr[kb] = *(const bf16x8*)&TB[n * 2048 + flat];
    }
    float yb = b2f(Ybias_b[v * 64 + q * 16 + n15]);
    for (int jt = e0; jt < e1; jt += 16) {
      int je = jt + n15; if (je > e1 - 1) je = e1 - 1;
      int e = order[je];                          // A row = edge (lane&15)
      f32x4 acc = {0.f, 0.f, 0.f, 0.f};
#pragma unroll
      for (int kb = 0; kb < 4; ++kb) {
        union { uint4 u; bf16x8 v; } af;
        af.u = *(const uint4*)(r1b + e * 128 + kb * 32 + quad * 8);
        acc = __builtin_amdgcn_mfma_f32_16x16x32_bf16(af.v, bfr[kb], acc, 0, 0, 0);
      }
#pragma unroll
      for (int r = 0; r < 4; ++r) {
        int row = quad * 4 + r;                   // D row = edge index in tile
        if (jt + row < e1) {
          int er = order[jt + row];
          atomicAdd(&agg[dst[er] * 64 + q * 16 + n15], acc[r] + yb);
        }
      }
    }
  }
}

// ---------------- GRU cell, 4 nodes/block, in-place on h ----------------
__global__ __launch_bounds__(256) void k_gru(
    const float* __restrict__ agg, float* __restrict__ h,
    const float* __restrict__ WtIH, const float* __restrict__ WtHH,
    const float* __restrict__ b_ih, const float* __restrict__ b_hh) {
  int t = threadIdx.x;
  int n = t >> 6, o = t & 63;
  int v = blockIdx.x * 4 + n;
  __shared__ float x[4][D], hp[4][D];
  x[n][o] = fmaxf(agg[v * D + o], 0.f);
  hp[n][o] = h[v * D + o];
  __syncthreads();
  float gr = b_ih[o],     gz = b_ih[D + o],  gn = b_ih[2 * D + o];
  float hr = b_hh[o],     hz = b_hh[D + o],  hn = b_hh[2 * D + o];
  for (int i = 0; i < D; ++i) {
    float xi = x[n][i], hi = hp[n][i];
    const float* wi = WtIH + i * 192;
    const float* wh = WtHH + i * 192;
    gr += wi[o] * xi;       gz += wi[D + o] * xi;       gn += wi[2 * D + o] * xi;
    hr += wh[o] * hi;       hz += wh[D + o] * hi;       hn += wh[2 * D + o] * hi;
  }
  float r = sigf(gr + hr);
  float z = sigf(gz + hz);
  float nn = tanhf(gn + r * hn);
  h[v * D + o] = (1.f - z) * nn + z * hp[n][o];
}

// ---------------- Set2Set (6 iters, 3-layer LSTM) + predict head ----------------
__global__ __launch_bounds__(256) void k_s2s(
    const float* __restrict__ h,
    const float* __restrict__ WT0, const float* __restrict__ WT1,
    const float* __restrict__ WT2, const float* __restrict__ bsum,
    const float* __restrict__ W_p1, const float* __restrict__ b_p1,
    const float* __restrict__ W_p2, const float* __restrict__ b_p2,
    float* __restrict__ out) {
  int g = blockIdx.x, t = threadIdx.x;            // 256 threads
  __shared__ float hL[NPG * 65];                  // padded graph h-block
  __shared__ float hsL[3][D], csL[3][D], q_star[2 * D], xc[192], gates[256],
                   att[NPG], scal[2];
  for (int idx = t; idx < NPG * 64; idx += 256)
    hL[(idx >> 6) * 65 + (idx & 63)] = h[(size_t)g * NPG * 64 + idx];
  if (t < D) {
    hsL[0][t] = 0.f; hsL[1][t] = 0.f; hsL[2][t] = 0.f;
    csL[0][t] = 0.f; csL[1][t] = 0.f; csL[2][t] = 0.f;
  }
  if (t < 2 * D) q_star[t] = 0.f;
  __syncthreads();
  for (int it = 0; it < S2S_ITERS; ++it) {
    if (t < 128) xc[t] = q_star[t];
    if (t < 64) xc[128 + t] = hsL[0][t];
    __syncthreads();
    {
      float gacc = bsum[t];
#pragma unroll 16
      for (int k = 0; k < 192; ++k) gacc += WT0[k * 256 + t] * xc[k];
      gates[t] = gacc;
    }
    __syncthreads();
    if (t < 64) {
      float c = sigf(gates[64 + t]) * csL[0][t] + sigf(gates[t]) * tanhf(gates[128 + t]);
      csL[0][t] = c;
      hsL[0][t] = sigf(gates[192 + t]) * tanhf(c);
    }
    __syncthreads();
    for (int l = 1; l < 3; ++l) {
      const float* WT = (l == 1) ? WT1 : WT2;
      if (t < 64) { xc[t] = hsL[l - 1][t]; xc[64 + t] = hsL[l][t]; }
      __syncthreads();
      float gacc = bsum[l * 256 + t];
#pragma unroll 16
      for (int k = 0; k < 128; ++k) gacc += WT[k * 256 + t] * xc[k];
      gates[t] = gacc;
      __syncthreads();
      if (t < 64) {
        float c = sigf(gates[64 + t]) * csL[l][t] + sigf(gates[t]) * tanhf(gates[128 + t]);
        csL[l][t] = c;
        hsL[l][t] = sigf(gates[192 + t]) * tanhf(c);
      }
      __syncthreads();
    }
    if (t < NPG) {
      float e = 0.f;
#pragma unroll 8
      for (int dd = 0; dd < D; ++dd) e += hL[t * 65 + dd] * hsL[2][dd];
      att[t] = e;
    }
    __syncthreads();
    if (t == 0) {
      float m = att[0];
      for (int n = 1; n < NPG; ++n) m = fmaxf(m, att[n]);
      scal[0] = m;
    }
    __syncthreads();
    if (t < NPG) att[t] = expf(att[t] - scal[0]);
    __syncthreads();
    if (t == 0) {
      float s = 0.f;
      for (int n = 0; n < NPG; ++n) s += att[n];
      scal[1] = 1.f / s;
    }
    __syncthreads();
    if (t < D) {
      float r = 0.f;
#pragma unroll 4
      for (int n = 0; n < NPG; ++n) r += hL[n * 65 + t] * att[n];
      q_star[t] = hsL[2][t];
      q_star[D + t] = r * scal[1];
    }
    __syncthreads();
  }
  if (t < D) {
    float p = b_p1[t];
    for (int k = 0; k < 2 * D; ++k) p += q_star[k] * W_p1[k * D + t];
    p = fmaxf(p, 0.f);
    att[t] = p * W_p2[t];
  }
  __syncthreads();
  if (t == 0) {
    float s = 0.f;
    for (int j = 0; j < D; ++j) s += att[j];
    out[g] = s + b_p2[0];
  }
}

extern "C" void kernel_launch(void* const* d_in, const int* in_sizes, int n_in,
                              void* d_out, int out_size, void* d_ws, size_t ws_size,
                              hipStream_t stream) {
  const float* node_feats = (const float*)d_in[0];
  const float* edge_feats = (const float*)d_in[1];
  const int*   src        = (const int*)d_in[2];
  const int*   dst        = (const int*)d_in[3];
  // d_in[4] graph_ids: contiguous 100-node segments by construction
  const float* W_proj = (const float*)d_in[5];
  const float* b_proj = (const float*)d_in[6];
  const float* W_e1   = (const float*)d_in[7];
  const float* b_e1   = (const float*)d_in[8];
  const float* W_e2   = (const float*)d_in[9];
  const float* b_e2   = (const float*)d_in[10];
  const float* b_conv = (const float*)d_in[11];
  const float* W_ih   = (const float*)d_in[12];
  const float* W_hh   = (const float*)d_in[13];
  const float* b_ih   = (const float*)d_in[14];
  const float* b_hh   = (const float*)d_in[15];
  const float* Wih0 = (const float*)d_in[16]; const float* Whh0 = (const float*)d_in[17];
  const float* bih0 = (const float*)d_in[18]; const float* bhh0 = (const float*)d_in[19];
  const float* Wih1 = (const float*)d_in[20]; const float* Whh1 = (const float*)d_in[21];
  const float* bih1 = (const float*)d_in[22]; const float* bhh1 = (const float*)d_in[23];
  const float* Wih2 = (const float*)d_in[24]; const float* Whh2 = (const float*)d_in[25];
  const float* bih2 = (const float*)d_in[26]; const float* bhh2 = (const float*)d_in[27];
  const float* W_p1 = (const float*)d_in[28]; const float* b_p1 = (const float*)d_in[29];
  const float* W_p2 = (const float*)d_in[30]; const float* b_p2 = (const float*)d_in[31];

  // ---- workspace layout (total ~14.60 MB; <= proven-safe 14.65 MB) ----
  char* ws = (char*)d_ws;
  float* h      = (float*)(ws + 0);               // 1,024,000
  float* agg    = (float*)(ws + 1024000);         // 1,024,000
  u16b*  r1b    = (u16b*) (ws + 2048000);         // 10,240,000
  float* WtIH   = (float*)(ws + 12288000);        // 49,152
  float* WtHH   = (float*)(ws + 12337152);        // 49,152
  int*   offs   = (int*)  (ws + 12386304);        // 16,384 (4096 bins)
  int*   cursor = (int*)  (ws + 12402688);        // 16,384
  int*   order  = (int*)  (ws + 12419072);        // 160,000
  u16b*  W2s    = (u16b*) (ws + 12579072);        // 1,048,576 (fragment-permuted)
  float* WT0    = (float*)(ws + 13627648);        // 196,608
  float* WT1    = (float*)(ws + 13824256);        // 131,072
  float* WT2    = (float*)(ws + 13955328);        // 131,072
  float* bsum   = (float*)(ws + 14086400);        // 3,072
  u16b*  Ybias  = (u16b*) (ws + 14089472);        // 512,000 -> end 14,601,472

  k_proj<<<V_N, 64, 0, stream>>>(node_feats, W_proj, b_proj, h);
  k_prep<<<2048, 256, 0, stream>>>(W_ih, W_hh, W_e2,
      Wih0, Whh0, bih0, bhh0, Wih1, Whh1, bih1, bhh1, Wih2, Whh2, bih2, bhh2,
      WtIH, WtHH, W2s, WT0, WT1, WT2, bsum);
  k_edge1<<<E_N / 8, 128, 0, stream>>>(edge_feats, W_e1, b_e1, r1b);
  // counting sort by src (uses cursor as counts first)
  k_zero<<<16, 256, 0, stream>>>(cursor);
  k_hist<<<(E_N + 255) / 256, 256, 0, stream>>>(src, cursor);
  k_scan<<<1, 256, 0, stream>>>(cursor, offs, cursor);
  k_scatter<<<(E_N + 255) / 256, 256, 0, stream>>>(src, cursor, order);

  for (int s = 0; s < NSTEPS; ++s) {
    k_ybias<<<V_N, 64, 0, stream>>>(h, b_e2, Ybias);
    k_init_agg<<<(V_N * D) / 256, 256, 0, stream>>>(agg, b_conv);
    k_msg6<<<(V_N / 16) * 4, 256, 0, stream>>>(h, r1b, W2s, Ybias,
                                               offs, order, dst, agg);
    k_gru<<<V_N / 4, 256, 0, stream>>>(agg, h, WtIH, WtHH, b_ih, b_hh);
  }
  k_s2s<<<G_N, 256, 0, stream>>>(h, WT0, WT1, WT2, bsum,
      W_p1, b_p1, W_p2, b_p2, (float*)d_out);
}

// Round 9
// 556.638 us; speedup vs baseline: 6.0641x; 1.2530x over previous
//
#include <hip/hip_runtime.h>
#include <hip/hip_bf16.h>
#include <cstdint>
#include <cstddef>

#define D 64
#define V_N 4000
#define E_N 40000
#define G_N 40
#define NPG 100          // nodes per graph (contiguous)
#define NODE_IN 74
#define EDGE_IN 128
#define NSTEPS 6
#define S2S_ITERS 6

typedef unsigned short u16b;
typedef __attribute__((ext_vector_type(8))) short bf16x8;
typedef __attribute__((ext_vector_type(4))) float f32x4;

__device__ __forceinline__ float b2f(u16b u) {
  union { unsigned int i; float f; } v; v.i = ((unsigned int)u) << 16; return v.f;
}
__device__ __forceinline__ u16b f2b(float f) {
  union { unsigned int i; float f; } v; v.f = f;
  unsigned int r = (v.i + 0x7fffu + ((v.i >> 16) & 1u)) >> 16;
  return (u16b)r;
}
__device__ __forceinline__ float sigf(float x) { return 1.f / (1.f + expf(-x)); }

// ---------------- h = relu(node_feats @ W_proj + b_proj) ----------------
__global__ void k_proj(const float* __restrict__ nf, const float* __restrict__ W,
                       const float* __restrict__ b, float* __restrict__ h) {
  int v = blockIdx.x, o = threadIdx.x;            // 64 threads
  const float* row = nf + v * NODE_IN;
  float acc = b[o];
  for (int i = 0; i < NODE_IN; ++i)
    acc += row[i] * W[i * D + o];
  h[v * D + o] = fmaxf(acc, 0.f);
}

// ------- prep: GRU transpose + W2 fragment permutation + packed LSTM WT ----
__global__ void k_prep(const float* __restrict__ W_ih, const float* __restrict__ W_hh,
                       const float* __restrict__ W_e2,
                       const float* __restrict__ Wih0, const float* __restrict__ Whh0,
                       const float* __restrict__ bih0, const float* __restrict__ bhh0,
                       const float* __restrict__ Wih1, const float* __restrict__ Whh1,
                       const float* __restrict__ bih1, const float* __restrict__ bhh1,
                       const float* __restrict__ Wih2, const float* __restrict__ Whh2,
                       const float* __restrict__ bih2, const float* __restrict__ bhh2,
                       float* __restrict__ WtIH, float* __restrict__ WtHH,
                       u16b* __restrict__ W2s,
                       unsigned* __restrict__ WP0, unsigned* __restrict__ WP1,
                       unsigned* __restrict__ WP2, float* __restrict__ bsum) {
  int idx = blockIdx.x * 256 + threadIdx.x;       // grid covers 524288
  if (idx < 192 * 64) {
    int j = idx >> 6, i = idx & 63;
    WtIH[i * 192 + j] = W_ih[j * 64 + i];
    WtHH[i * 192 + j] = W_hh[j * 64 + i];
  }
  if (idx < 524288) {
    int q = idx >> 17, rem = idx & 131071;
    int t16 = rem >> 10, rem2 = rem & 1023;
    int kbA = rem2 >> 9, rem3 = rem2 & 511;
    int lane = rem3 >> 3, jA = rem3 & 7;
    int m15 = lane & 15, quadA = lane >> 4;
    int m_idx = t16 * 16 + m15;
    int i = kbA * 32 + quadA * 8 + jA;
    int kb = m_idx >> 9, quadB = (m_idx >> 7) & 3;
    int n15B = (m_idx >> 3) & 15, j = m_idx & 7;
    int k = kb * 32 + quadB * 8 + j;
    int o = q * 16 + n15B;
    W2s[idx] = f2b(W_e2[k * 4096 + i * 64 + o]);
  }
  if (idx < 24576) {                              // WP0: layer0 packed bf16
    int kh = idx >> 8, tt = idx & 255;
    int half = kh / 48, kk = kh - half * 48;
    int k0 = half * 96 + 2 * kk;
    float v0 = (k0 < 128) ? Wih0[tt * 128 + k0] : Whh0[tt * 64 + (k0 - 128)];
    float v1 = (k0 + 1 < 128) ? Wih0[tt * 128 + k0 + 1] : Whh0[tt * 64 + (k0 - 127)];
    WP0[idx] = (unsigned)f2b(v0) | ((unsigned)f2b(v1) << 16);
  }
  if (idx < 16384) {                              // WP1/WP2: layers 1,2
    int kh = idx >> 8, tt = idx & 255;
    int half = kh >> 5, kk = kh & 31;
    int k0 = half * 64 + 2 * kk;
    float a0 = (k0 < 64) ? Wih1[tt * 64 + k0] : Whh1[tt * 64 + (k0 - 64)];
    float a1 = (k0 + 1 < 64) ? Wih1[tt * 64 + k0 + 1] : Whh1[tt * 64 + (k0 - 63)];
    WP1[idx] = (unsigned)f2b(a0) | ((unsigned)f2b(a1) << 16);
    float c0 = (k0 < 64) ? Wih2[tt * 64 + k0] : Whh2[tt * 64 + (k0 - 64)];
    float c1 = (k0 + 1 < 64) ? Wih2[tt * 64 + k0 + 1] : Whh2[tt * 64 + (k0 - 63)];
    WP2[idx] = (unsigned)f2b(c0) | ((unsigned)f2b(c1) << 16);
  }
  if (idx < 256) bsum[idx] = bih0[idx] + bhh0[idx];
  else if (idx < 512) bsum[idx] = bih1[idx - 256] + bhh1[idx - 256];
  else if (idx < 768) bsum[idx] = bih2[idx - 512] + bhh2[idx - 512];
}

// ---------------- r1 = relu(edge_feats @ W_e1 + b_e1) -> bf16 ----------------
__global__ void k_edge1(const float* __restrict__ ef, const float* __restrict__ W,
                        const float* __restrict__ b, u16b* __restrict__ r1b) {
  __shared__ float x[8][EDGE_IN];
  int t = threadIdx.x;                            // 128 threads
  int e0 = blockIdx.x * 8;
  for (int e = 0; e < 8; ++e)
    x[e][t] = ef[(e0 + e) * EDGE_IN + t];
  __syncthreads();
  float acc[8];
  float bb = b[t];
#pragma unroll
  for (int e = 0; e < 8; ++e) acc[e] = bb;
  for (int i = 0; i < EDGE_IN; ++i) {
    float w = W[i * 128 + t];
#pragma unroll
    for (int e = 0; e < 8; ++e) acc[e] += x[e][i] * w;
  }
  for (int e = 0; e < 8; ++e)
    r1b[(e0 + e) * 128 + t] = f2b(fmaxf(acc[e], 0.f));
}

// ---------------- counting sort of edges by src ----------------
__global__ void k_zero(int* __restrict__ cnt) {   // 4096 bins
  cnt[blockIdx.x * 256 + threadIdx.x] = 0;
}
__global__ void k_hist(const int* __restrict__ src, int* __restrict__ cnt) {
  int e = blockIdx.x * 256 + threadIdx.x;
  if (e < E_N) atomicAdd(&cnt[src[e]], 1);
}
__global__ __launch_bounds__(256) void k_scan(const int* __restrict__ cnt,
                                              int* __restrict__ offs,
                                              int* __restrict__ cursor) {
  __shared__ int part[256];
  int t = threadIdx.x;                            // single block
  int local[16], s = 0;
#pragma unroll
  for (int b = 0; b < 16; ++b) { local[b] = cnt[t * 16 + b]; s += local[b]; }
  part[t] = s;
  __syncthreads();
  for (int off = 1; off < 256; off <<= 1) {
    int v = (t >= off) ? part[t - off] : 0;
    __syncthreads();
    part[t] += v;
    __syncthreads();
  }
  int run = part[t] - s;                          // exclusive base
#pragma unroll
  for (int b = 0; b < 16; ++b) {
    offs[t * 16 + b] = run;
    cursor[t * 16 + b] = run;
    run += local[b];
  }
}
__global__ void k_scatter(const int* __restrict__ src, int* __restrict__ cursor,
                          int* __restrict__ order) {
  int e = blockIdx.x * 256 + threadIdx.x;
  if (e < E_N) {
    int pos = atomicAdd(&cursor[src[e]], 1);
    order[pos] = e;
  }
}

// ---------------- zero agg once (per-step reset happens in k_gru) -----------
__global__ void k_zero_agg(float* __restrict__ agg) {
  agg[blockIdx.x * 256 + threadIdx.x] = 0.f;
}

// ------ block = 16 nodes x 1 o-quarter, 512 threads (8 waves).
// Phase A: T[16n][128k][16o] + ybias via MFMA. Phase B: edge-tile MFMA.
__global__ __launch_bounds__(512) void k_msg7(
    const float* __restrict__ h, const u16b* __restrict__ r1b,
    const u16b* __restrict__ W2s, const float* __restrict__ b_e2,
    const int* __restrict__ offs, const int* __restrict__ order,
    const int* __restrict__ dst, float* __restrict__ agg) {
  __shared__ __align__(16) u16b TB[16 * 2048];    // 64 KB exactly
  __shared__ float ybs[16][16];
  int t = threadIdx.x;
  int g = blockIdx.x >> 2, q = blockIdx.x & 3;
  int v0 = g * 16;
  int w = t >> 6, lane = t & 63;
  int n15 = lane & 15, quad = lane >> 4;

  // B-fragments from h (node = n15, i = quad*8+j (+32 for kbA=1))
  bf16x8 hb[2];
  {
    union { bf16x8 v; u16b s[8]; } b0, b1;
    const float* hp = h + (v0 + n15) * 64 + quad * 8;
#pragma unroll
    for (int j = 0; j < 8; ++j) { b0.s[j] = f2b(hp[j]); b1.s[j] = f2b(hp[32 + j]); }
    hb[0] = b0.v; hb[1] = b1.v;
  }
  // wave 0: ybias[node][o_local] via MFMA with A = b_e2 fragment
  if (w == 0) {
    union { bf16x8 v; u16b s[8]; } a0, a1;
#pragma unroll
    for (int j = 0; j < 8; ++j) {
      a0.s[j] = f2b(b_e2[(quad * 8 + j) * 64 + q * 16 + n15]);
      a1.s[j] = f2b(b_e2[(32 + quad * 8 + j) * 64 + q * 16 + n15]);
    }
    f32x4 acc = {0.f, 0.f, 0.f, 0.f};
    acc = __builtin_amdgcn_mfma_f32_16x16x32_bf16(a0.v, hb[0], acc, 0, 0, 0);
    acc = __builtin_amdgcn_mfma_f32_16x16x32_bf16(a1.v, hb[1], acc, 0, 0, 0);
#pragma unroll
    for (int r = 0; r < 4; ++r) ybs[n15][quad * 4 + r] = acc[r];
  }
  // Phase A: wave w owns m-tiles t16 = w*16 .. w*16+15
  const uint4* W4 = (const uint4*)(W2s) + (size_t)q * 16384;
#pragma unroll 4
  for (int tt = 0; tt < 16; ++tt) {
    int t16 = w * 16 + tt;
    uint4 a0 = W4[t16 * 128 + lane];
    uint4 a1 = W4[t16 * 128 + 64 + lane];
    union { uint4 u; bf16x8 v; } c0, c1;
    c0.u = a0; c1.u = a1;
    f32x4 acc = {0.f, 0.f, 0.f, 0.f};
    acc = __builtin_amdgcn_mfma_f32_16x16x32_bf16(c0.v, hb[0], acc, 0, 0, 0);
    acc = __builtin_amdgcn_mfma_f32_16x16x32_bf16(c1.v, hb[1], acc, 0, 0, 0);
    // D[row = quad*4+r][col = node n15] -> TB[n15][m_row], +n15*8 rotation
    int flat = (t16 * 16 + quad * 4 + n15 * 8) & 2047;
    uint2 pk;
    pk.x = (unsigned)f2b(acc[0]) | ((unsigned)f2b(acc[1]) << 16);
    pk.y = (unsigned)f2b(acc[2]) | ((unsigned)f2b(acc[3]) << 16);
    *(uint2*)&TB[n15 * 2048 + flat] = pk;
  }
  __syncthreads();

  // Phase B: wave w handles nodes w*2, w*2+1
  for (int ni = 0; ni < 2; ++ni) {
    int n = w * 2 + ni;
    int v = v0 + n;
    int e0 = offs[v], e1 = offs[v + 1];
    if (e0 >= e1) continue;
    bf16x8 bfr[4];                                // B-frags: one b128 each
#pragma unroll
    for (int kb = 0; kb < 4; ++kb) {
      int flat = (((kb * 64 + quad * 16 + n15) << 3) + n * 8) & 2047;
      bfr[kb] = *(const bf16x8*)&TB[n * 2048 + flat];
    }
    float yb = ybs[n][n15];
    for (int jt = e0; jt < e1; jt += 16) {
      int je = jt + n15; if (je > e1 - 1) je = e1 - 1;
      int e = order[je];                          // A row = edge (lane&15)
      f32x4 acc = {0.f, 0.f, 0.f, 0.f};
#pragma unroll
      for (int kb = 0; kb < 4; ++kb) {
        union { uint4 u; bf16x8 v; } af;
        af.u = *(const uint4*)(r1b + e * 128 + kb * 32 + quad * 8);
        acc = __builtin_amdgcn_mfma_f32_16x16x32_bf16(af.v, bfr[kb], acc, 0, 0, 0);
      }
#pragma unroll
      for (int r = 0; r < 4; ++r) {
        int row = quad * 4 + r;                   // D row = edge index in tile
        if (jt + row < e1) {
          int er = order[jt + row];
          atomicAdd(&agg[dst[er] * 64 + q * 16 + n15], acc[r] + yb);
        }
      }
    }
  }
}

// ---------------- GRU cell, 4 nodes/block; resets agg for next step --------
__global__ __launch_bounds__(256) void k_gru(
    float* __restrict__ agg, float* __restrict__ h,
    const float* __restrict__ WtIH, const float* __restrict__ WtHH,
    const float* __restrict__ b_ih, const float* __restrict__ b_hh,
    const float* __restrict__ b_conv) {
  int t = threadIdx.x;
  int n = t >> 6, o = t & 63;
  int v = blockIdx.x * 4 + n;
  __shared__ float x[4][D], hp[4][D];
  x[n][o] = fmaxf(agg[v * D + o] + b_conv[o], 0.f);
  agg[v * D + o] = 0.f;                           // ready for next step's atomics
  hp[n][o] = h[v * D + o];
  __syncthreads();
  float gr = b_ih[o],     gz = b_ih[D + o],  gn = b_ih[2 * D + o];
  float hr = b_hh[o],     hz = b_hh[D + o],  hn = b_hh[2 * D + o];
  for (int i = 0; i < D; ++i) {
    float xi = x[n][i], hi = hp[n][i];
    const float* wi = WtIH + i * 192;
    const float* wh = WtHH + i * 192;
    gr += wi[o] * xi;       gz += wi[D + o] * xi;       gn += wi[2 * D + o] * xi;
    hr += wh[o] * hi;       hz += wh[D + o] * hi;       hn += wh[2 * D + o] * hi;
  }
  float r = sigf(gr + hr);
  float z = sigf(gz + hz);
  float nn = tanhf(gn + r * hn);
  h[v * D + o] = (1.f - z) * nn + z * hp[n][o];
}

// ------- Set2Set: 512 threads, register-resident bf16 LSTM weights ---------
__global__ __launch_bounds__(512) void k_s2s(
    const float* __restrict__ h,
    const unsigned* __restrict__ WP0, const unsigned* __restrict__ WP1,
    const unsigned* __restrict__ WP2, const float* __restrict__ bsum,
    const float* __restrict__ W_p1, const float* __restrict__ b_p1,
    const float* __restrict__ W_p2, const float* __restrict__ b_p2,
    float* __restrict__ out) {
  int g = blockIdx.x, t = threadIdx.x;            // 512 threads
  int tt = t & 255, half = t >> 8;
  __shared__ float hL[NPG * 65];
  __shared__ float hsL[3][D], csL[3][D], q_star[2 * D], xc[192], gates[256];
  __shared__ float gpart[512], att[NPG], scal[2], rpart[2][D];
  // preload packed bf16 weights into registers (held across all 6 iterations)
  unsigned w0[48], w1[32], w2[32];
#pragma unroll
  for (int kk = 0; kk < 48; ++kk) w0[kk] = WP0[(half * 48 + kk) * 256 + tt];
#pragma unroll
  for (int kk = 0; kk < 32; ++kk) w1[kk] = WP1[(half * 32 + kk) * 256 + tt];
#pragma unroll
  for (int kk = 0; kk < 32; ++kk) w2[kk] = WP2[(half * 32 + kk) * 256 + tt];
  for (int idx = t; idx < NPG * 64; idx += 512)
    hL[(idx >> 6) * 65 + (idx & 63)] = h[(size_t)g * NPG * 64 + idx];
  if (t < D) {
    hsL[0][t] = 0.f; hsL[1][t] = 0.f; hsL[2][t] = 0.f;
    csL[0][t] = 0.f; csL[1][t] = 0.f; csL[2][t] = 0.f;
  }
  if (t < 2 * D) q_star[t] = 0.f;
  __syncthreads();
  for (int it = 0; it < S2S_ITERS; ++it) {
    // ---- layer 0 (k: 128 q_star + 64 hidden) ----
    if (t < 128) xc[t] = q_star[t];
    if (t < 64) xc[128 + t] = hsL[0][t];
    __syncthreads();
    {
      float p = 0.f;
      int base = half * 96;
#pragma unroll
      for (int kk = 0; kk < 48; ++kk) {
        unsigned wv = w0[kk];
        p += b2f((u16b)(wv & 0xffffu)) * xc[base + 2 * kk];
        p += b2f((u16b)(wv >> 16)) * xc[base + 2 * kk + 1];
      }
      gpart[t] = p;
    }
    __syncthreads();
    if (t < 256) gates[t] = bsum[t] + gpart[t] + gpart[t + 256];
    __syncthreads();
    if (t < 64) {
      float c = sigf(gates[64 + t]) * csL[0][t] + sigf(gates[t]) * tanhf(gates[128 + t]);
      csL[0][t] = c;
      hsL[0][t] = sigf(gates[192 + t]) * tanhf(c);
    }
    __syncthreads();
    // ---- layer 1 ----
    if (t < 64) { xc[t] = hsL[0][t]; xc[64 + t] = hsL[1][t]; }
    __syncthreads();
    {
      float p = 0.f;
      int base = half * 64;
#pragma unroll
      for (int kk = 0; kk < 32; ++kk) {
        unsigned wv = w1[kk];
        p += b2f((u16b)(wv & 0xffffu)) * xc[base + 2 * kk];
        p += b2f((u16b)(wv >> 16)) * xc[base + 2 * kk + 1];
      }
      gpart[t] = p;
    }
    __syncthreads();
    if (t < 256) gates[t] = bsum[256 + t] + gpart[t] + gpart[t + 256];
    __syncthreads();
    if (t < 64) {
      float c = sigf(gates[64 + t]) * csL[1][t] + sigf(gates[t]) * tanhf(gates[128 + t]);
      csL[1][t] = c;
      hsL[1][t] = sigf(gates[192 + t]) * tanhf(c);
    }
    __syncthreads();
    // ---- layer 2 ----
    if (t < 64) { xc[t] = hsL[1][t]; xc[64 + t] = hsL[2][t]; }
    __syncthreads();
    {
      float p = 0.f;
      int base = half * 64;
#pragma unroll
      for (int kk = 0; kk < 32; ++kk) {
        unsigned wv = w2[kk];
        p += b2f((u16b)(wv & 0xffffu)) * xc[base + 2 * kk];
        p += b2f((u16b)(wv >> 16)) * xc[base + 2 * kk + 1];
      }
      gpart[t] = p;
    }
    __syncthreads();
    if (t < 256) gates[t] = bsum[512 + t] + gpart[t] + gpart[t + 256];
    __syncthreads();
    if (t < 64) {
      float c = sigf(gates[64 + t]) * csL[2][t] + sigf(gates[t]) * tanhf(gates[128 + t]);
      csL[2][t] = c;
      hsL[2][t] = sigf(gates[192 + t]) * tanhf(c);
    }
    __syncthreads();
    // ---- attention over the graph's 100 nodes ----
    if (t < NPG) {
      float e = 0.f;
#pragma unroll 8
      for (int dd = 0; dd < D; ++dd) e += hL[t * 65 + dd] * hsL[2][dd];
      att[t] = e;
    }
    __syncthreads();
    if (t < 64) {                                 // wave-0 max reduction
      float m = att[t];
      if (t + 64 < NPG) m = fmaxf(m, att[t + 64]);
#pragma unroll
      for (int off = 32; off >= 1; off >>= 1)
        m = fmaxf(m, __shfl_xor(m, off));
      if (t == 0) scal[0] = m;
    }
    __syncthreads();
    if (t < NPG) att[t] = expf(att[t] - scal[0]);
    __syncthreads();
    if (t < 64) {                                 // wave-0 sum reduction
      float s = att[t] + ((t + 64 < NPG) ? att[t + 64] : 0.f);
#pragma unroll
      for (int off = 32; off >= 1; off >>= 1)
        s += __shfl_xor(s, off);
      if (t == 0) scal[1] = 1.f / s;
    }
    __syncthreads();
    if (t < 64) {                                 // readout halves
      float r = 0.f;
      for (int n = 0; n < 50; ++n) r += hL[n * 65 + t] * att[n];
      rpart[0][t] = r;
    } else if (t >= 256 && t < 320) {
      int o = t - 256;
      float r = 0.f;
      for (int n = 50; n < NPG; ++n) r += hL[n * 65 + o] * att[n];
      rpart[1][o] = r;
    }
    __syncthreads();
    if (t < 64) {
      q_star[t] = hsL[2][t];
      q_star[D + t] = (rpart[0][t] + rpart[1][t]) * scal[1];
    }
    __syncthreads();
  }
  // predict: relu(q_star @ W_p1 + b_p1) @ W_p2 + b_p2
  if (t < 64) {
    float p = b_p1[t];
    for (int k = 0; k < 2 * D; ++k) p += q_star[k] * W_p1[k * D + t];
    p = fmaxf(p, 0.f);
    att[t] = p * W_p2[t];
  }
  __syncthreads();
  if (t == 0) {
    float s = 0.f;
    for (int j = 0; j < D; ++j) s += att[j];
    out[g] = s + b_p2[0];
  }
}

extern "C" void kernel_launch(void* const* d_in, const int* in_sizes, int n_in,
                              void* d_out, int out_size, void* d_ws, size_t ws_size,
                              hipStream_t stream) {
  const float* node_feats = (const float*)d_in[0];
  const float* edge_feats = (const float*)d_in[1];
  const int*   src        = (const int*)d_in[2];
  const int*   dst        = (const int*)d_in[3];
  // d_in[4] graph_ids: contiguous 100-node segments by construction
  const float* W_proj = (const float*)d_in[5];
  const float* b_proj = (const float*)d_in[6];
  const float* W_e1   = (const float*)d_in[7];
  const float* b_e1   = (const float*)d_in[8];
  const float* W_e2   = (const float*)d_in[9];
  const float* b_e2   = (const float*)d_in[10];
  const float* b_conv = (const float*)d_in[11];
  const float* W_ih   = (const float*)d_in[12];
  const float* W_hh   = (const float*)d_in[13];
  const float* b_ih   = (const float*)d_in[14];
  const float* b_hh   = (const float*)d_in[15];
  const float* Wih0 = (const float*)d_in[16]; const float* Whh0 = (const float*)d_in[17];
  const float* bih0 = (const float*)d_in[18]; const float* bhh0 = (const float*)d_in[19];
  const float* Wih1 = (const float*)d_in[20]; const float* Whh1 = (const float*)d_in[21];
  const float* bih1 = (const float*)d_in[22]; const float* bhh1 = (const float*)d_in[23];
  const float* Wih2 = (const float*)d_in[24]; const float* Whh2 = (const float*)d_in[25];
  const float* bih2 = (const float*)d_in[26]; const float* bhh2 = (const float*)d_in[27];
  const float* W_p1 = (const float*)d_in[28]; const float* b_p1 = (const float*)d_in[29];
  const float* W_p2 = (const float*)d_in[30]; const float* b_p2 = (const float*)d_in[31];

  // ---- workspace layout (total ~13.9 MB; <= proven-safe 14.65 MB) ----
  char* ws = (char*)d_ws;
  float* h      = (float*)(ws + 0);               // 1,024,000
  float*    agg = (float*)(ws + 1024000);         // 1,024,000
  u16b*  r1b    = (u16b*) (ws + 2048000);         // 10,240,000
  float* WtIH   = (float*)(ws + 12288000);        // 49,152
  float* WtHH   = (float*)(ws + 12337152);        // 49,152
  int*   offs   = (int*)  (ws + 12386304);        // 16,384 (4096 bins)
  int*   cursor = (int*)  (ws + 12402688);        // 16,384
  int*   order  = (int*)  (ws + 12419072);        // 160,000
  u16b*  W2s    = (u16b*) (ws + 12579072);        // 1,048,576 (fragment-permuted)
  unsigned* WP0 = (unsigned*)(ws + 13627648);     // 98,304
  unsigned* WP1 = (unsigned*)(ws + 13725952);     // 65,536
  unsigned* WP2 = (unsigned*)(ws + 13791488);     // 65,536
  float* bsum   = (float*)(ws + 13857024);        // 3,072 -> end 13,860,096

  k_proj<<<V_N, 64, 0, stream>>>(node_feats, W_proj, b_proj, h);
  k_prep<<<2048, 256, 0, stream>>>(W_ih, W_hh, W_e2,
      Wih0, Whh0, bih0, bhh0, Wih1, Whh1, bih1, bhh1, Wih2, Whh2, bih2, bhh2,
      WtIH, WtHH, W2s, WP0, WP1, WP2, bsum);
  k_edge1<<<E_N / 8, 128, 0, stream>>>(edge_feats, W_e1, b_e1, r1b);
  // counting sort by src (uses cursor as counts first)
  k_zero<<<16, 256, 0, stream>>>(cursor);
  k_hist<<<(E_N + 255) / 256, 256, 0, stream>>>(src, cursor);
  k_scan<<<1, 256, 0, stream>>>(cursor, offs, cursor);
  k_scatter<<<(E_N + 255) / 256, 256, 0, stream>>>(src, cursor, order);
  k_zero_agg<<<(V_N * D) / 256, 256, 0, stream>>>(agg);

  for (int s = 0; s < NSTEPS; ++s) {
    k_msg7<<<(V_N / 16) * 4, 512, 0, stream>>>(h, r1b, W2s, b_e2,
                                               offs, order, dst, agg);
    k_gru<<<V_N / 4, 256, 0, stream>>>(agg, h, WtIH, WtHH, b_ih, b_hh, b_conv);
  }
  k_s2s<<<G_N, 512, 0, stream>>>(h, WP0, WP1, WP2, bsum,
      W_p1, b_p1, W_p2, b_p2, (float*)d_out);
}

// Round 10
// 506.271 us; speedup vs baseline: 6.6674x; 1.0995x over previous
//
#include <hip/hip_runtime.h>
#include <hip/hip_bf16.h>
#include <cstdint>
#include <cstddef>

#define D 64
#define V_N 4000
#define E_N 40000
#define G_N 40
#define NPG 100          // nodes per graph (contiguous)
#define NODE_IN 74
#define EDGE_IN 128
#define NSTEPS 6
#define S2S_ITERS 6

typedef unsigned short u16b;
typedef __attribute__((ext_vector_type(8))) short bf16x8;
typedef __attribute__((ext_vector_type(4))) float f32x4;

__device__ __forceinline__ float b2f(u16b u) {
  union { unsigned int i; float f; } v; v.i = ((unsigned int)u) << 16; return v.f;
}
__device__ __forceinline__ u16b f2b(float f) {
  union { unsigned int i; float f; } v; v.f = f;
  unsigned int r = (v.i + 0x7fffu + ((v.i >> 16) & 1u)) >> 16;
  return (u16b)r;
}
__device__ __forceinline__ float sigf(float x) { return 1.f / (1.f + expf(-x)); }

// ---------------- h = relu(node_feats @ W_proj + b_proj) ----------------
__global__ void k_proj(const float* __restrict__ nf, const float* __restrict__ W,
                       const float* __restrict__ b, float* __restrict__ h) {
  int v = blockIdx.x, o = threadIdx.x;            // 64 threads
  const float* row = nf + v * NODE_IN;
  float acc = b[o];
  for (int i = 0; i < NODE_IN; ++i)
    acc += row[i] * W[i * D + o];
  h[v * D + o] = fmaxf(acc, 0.f);
}

// ------- prep: all weight repacks (fragments + packed LSTM + bias sums) -----
__global__ void k_prep(const float* __restrict__ W_ih, const float* __restrict__ W_hh,
                       const float* __restrict__ W_e2, const float* __restrict__ W_e1,
                       const float* __restrict__ Wih0, const float* __restrict__ Whh0,
                       const float* __restrict__ bih0, const float* __restrict__ bhh0,
                       const float* __restrict__ Wih1, const float* __restrict__ Whh1,
                       const float* __restrict__ bih1, const float* __restrict__ bhh1,
                       const float* __restrict__ Wih2, const float* __restrict__ Whh2,
                       const float* __restrict__ bih2, const float* __restrict__ bhh2,
                       u16b* __restrict__ W2s,
                       unsigned* __restrict__ WP0, unsigned* __restrict__ WP1,
                       unsigned* __restrict__ WP2, float* __restrict__ bsum,
                       u16b* __restrict__ WIHf, u16b* __restrict__ WHHf,
                       u16b* __restrict__ W1f) {
  int idx = blockIdx.x * 256 + threadIdx.x;       // grid covers 524288
  if (idx < 524288) {                             // W_e2 -> Phase-A fragments
    int q = idx >> 17, rem = idx & 131071;
    int t16 = rem >> 10, rem2 = rem & 1023;
    int kbA = rem2 >> 9, rem3 = rem2 & 511;
    int lane = rem3 >> 3, jA = rem3 & 7;
    int m15 = lane & 15, quadA = lane >> 4;
    int m_idx = t16 * 16 + m15;
    int i = kbA * 32 + quadA * 8 + jA;
    int kb = m_idx >> 9, quadB = (m_idx >> 7) & 3;
    int n15B = (m_idx >> 3) & 15, j = m_idx & 7;
    int k = kb * 32 + quadB * 8 + j;
    int o = q * 16 + n15B;
    W2s[idx] = f2b(W_e2[k * 4096 + i * 64 + o]);
  }
  if (idx < 24576) {                              // WP0: layer0 packed bf16
    int kh = idx >> 8, tt = idx & 255;
    int half = kh / 48, kk = kh - half * 48;
    int k0 = half * 96 + 2 * kk;
    float v0 = (k0 < 128) ? Wih0[tt * 128 + k0] : Whh0[tt * 64 + (k0 - 128)];
    float v1 = (k0 + 1 < 128) ? Wih0[tt * 128 + k0 + 1] : Whh0[tt * 64 + (k0 - 127)];
    WP0[idx] = (unsigned)f2b(v0) | ((unsigned)f2b(v1) << 16);
  }
  if (idx < 16384) {                              // WP1/WP2: layers 1,2
    int kh = idx >> 8, tt = idx & 255;
    int half = kh >> 5, kk = kh & 31;
    int k0 = half * 64 + 2 * kk;
    float a0 = (k0 < 64) ? Wih1[tt * 64 + k0] : Whh1[tt * 64 + (k0 - 64)];
    float a1 = (k0 + 1 < 64) ? Wih1[tt * 64 + k0 + 1] : Whh1[tt * 64 + (k0 - 63)];
    WP1[idx] = (unsigned)f2b(a0) | ((unsigned)f2b(a1) << 16);
    float c0 = (k0 < 64) ? Wih2[tt * 64 + k0] : Whh2[tt * 64 + (k0 - 64)];
    float c1 = (k0 + 1 < 64) ? Wih2[tt * 64 + k0 + 1] : Whh2[tt * 64 + (k0 - 63)];
    WP2[idx] = (unsigned)f2b(c0) | ((unsigned)f2b(c1) << 16);
  }
  if (idx < 12288) {                              // GRU weights -> A-fragments
    int j = idx & 7, lane = (idx >> 3) & 63, tk = idx >> 9;
    int gt = tk >> 1, kb = tk & 1;
    int gate = gt * 16 + (lane & 15);
    int i = kb * 32 + ((lane >> 4) << 3) + j;
    WIHf[idx] = f2b(W_ih[gate * 64 + i]);
    WHHf[idx] = f2b(W_hh[gate * 64 + i]);
  }
  if (idx < 16384) {                              // W_e1 -> B-fragments
    int j = idx & 7, lane = (idx >> 3) & 63, tk = idx >> 9;
    int nt = tk >> 2, kb = tk & 3;
    int n = nt * 16 + (lane & 15);
    int i = kb * 32 + ((lane >> 4) << 3) + j;
    W1f[idx] = f2b(W_e1[i * 128 + n]);
  }
  if (idx < 256) bsum[idx] = bih0[idx] + bhh0[idx];
  else if (idx < 512) bsum[idx] = bih1[idx - 256] + bhh1[idx - 256];
  else if (idx < 768) bsum[idx] = bih2[idx - 512] + bhh2[idx - 512];
}

// -------- r1 = relu(edge_feats @ W_e1 + b_e1) -> bf16, via MFMA -------------
__global__ __launch_bounds__(256) void k_edge2(
    const float* __restrict__ ef, const u16b* __restrict__ W1f,
    const float* __restrict__ b_e1, u16b* __restrict__ r1b) {
  __shared__ __align__(16) u16b R[64 * 128];      // 16 KB
  int t = threadIdx.x, w = t >> 6, lane = t & 63;
  int n15 = lane & 15, quad = lane >> 4;
  int e0 = blockIdx.x * 64;
  int ew = e0 + w * 16;                           // wave's 16-edge m-tile
  bf16x8 aF[4];
  const float* ep = ef + (size_t)(ew + n15) * 128 + quad * 8;
#pragma unroll
  for (int kb = 0; kb < 4; ++kb) {
    union { bf16x8 v; u16b s[8]; } au;
#pragma unroll
    for (int j = 0; j < 8; ++j) au.s[j] = f2b(ep[kb * 32 + j]);
    aF[kb] = au.v;
  }
  const uint4* B4 = (const uint4*)W1f;
#pragma unroll
  for (int nt = 0; nt < 8; ++nt) {
    f32x4 acc = {0.f, 0.f, 0.f, 0.f};
#pragma unroll
    for (int kb = 0; kb < 4; ++kb) {
      union { uint4 u; bf16x8 v; } bu;
      bu.u = B4[(nt * 4 + kb) * 64 + lane];
      acc = __builtin_amdgcn_mfma_f32_16x16x32_bf16(aF[kb], bu.v, acc, 0, 0, 0);
    }
    float bb = b_e1[nt * 16 + n15];
#pragma unroll
    for (int r = 0; r < 4; ++r) {
      int eoff = w * 16 + quad * 4 + r;           // D row = edge offset
      R[eoff * 128 + nt * 16 + n15] = f2b(fmaxf(acc[r] + bb, 0.f));
    }
  }
  __syncthreads();
  const uint4* Rs = (const uint4*)R;
  uint4* out4 = (uint4*)(r1b + (size_t)e0 * 128);
  for (int i = t; i < 1024; i += 256) out4[i] = Rs[i];
}

// ---------------- counting sort of edges by src ----------------
__global__ void k_zero(int* __restrict__ cnt) {   // 4096 bins
  cnt[blockIdx.x * 256 + threadIdx.x] = 0;
}
__global__ void k_hist(const int* __restrict__ src, int* __restrict__ cnt) {
  int e = blockIdx.x * 256 + threadIdx.x;
  if (e < E_N) atomicAdd(&cnt[src[e]], 1);
}
__global__ __launch_bounds__(256) void k_scan(const int* __restrict__ cnt,
                                              int* __restrict__ offs,
                                              int* __restrict__ cursor) {
  __shared__ int part[256];
  int t = threadIdx.x;                            // single block
  int local[16], s = 0;
#pragma unroll
  for (int b = 0; b < 16; ++b) { local[b] = cnt[t * 16 + b]; s += local[b]; }
  part[t] = s;
  __syncthreads();
  for (int off = 1; off < 256; off <<= 1) {
    int v = (t >= off) ? part[t - off] : 0;
    __syncthreads();
    part[t] += v;
    __syncthreads();
  }
  int run = part[t] - s;                          // exclusive base
#pragma unroll
  for (int b = 0; b < 16; ++b) {
    offs[t * 16 + b] = run;
    cursor[t * 16 + b] = run;
    run += local[b];
  }
}
__global__ void k_scatter(const int* __restrict__ src, int* __restrict__ cursor,
                          int* __restrict__ order) {
  int e = blockIdx.x * 256 + threadIdx.x;
  if (e < E_N) {
    int pos = atomicAdd(&cursor[src[e]], 1);
    order[pos] = e;
  }
}

// ---------------- zero agg once (per-step reset happens in k_gru2) ----------
__global__ void k_zero_agg(float* __restrict__ agg) {
  agg[blockIdx.x * 256 + threadIdx.x] = 0.f;
}

// ------ block = 16 nodes x 1 o-quarter, 512 threads (8 waves).
// Phase A: T[16n][128k][16o] + ybias via MFMA. Phase B: edge-tile MFMA.
__global__ __launch_bounds__(512) void k_msg7(
    const float* __restrict__ h, const u16b* __restrict__ r1b,
    const u16b* __restrict__ W2s, const float* __restrict__ b_e2,
    const int* __restrict__ offs, const int* __restrict__ order,
    const int* __restrict__ dst, float* __restrict__ agg) {
  __shared__ __align__(16) u16b TB[16 * 2048];    // 64 KB exactly
  __shared__ float ybs[16][16];
  int t = threadIdx.x;
  int g = blockIdx.x >> 2, q = blockIdx.x & 3;
  int v0 = g * 16;
  int w = t >> 6, lane = t & 63;
  int n15 = lane & 15, quad = lane >> 4;

  bf16x8 hb[2];
  {
    union { bf16x8 v; u16b s[8]; } b0, b1;
    const float* hp = h + (v0 + n15) * 64 + quad * 8;
#pragma unroll
    for (int j = 0; j < 8; ++j) { b0.s[j] = f2b(hp[j]); b1.s[j] = f2b(hp[32 + j]); }
    hb[0] = b0.v; hb[1] = b1.v;
  }
  if (w == 0) {
    union { bf16x8 v; u16b s[8]; } a0, a1;
#pragma unroll
    for (int j = 0; j < 8; ++j) {
      a0.s[j] = f2b(b_e2[(quad * 8 + j) * 64 + q * 16 + n15]);
      a1.s[j] = f2b(b_e2[(32 + quad * 8 + j) * 64 + q * 16 + n15]);
    }
    f32x4 acc = {0.f, 0.f, 0.f, 0.f};
    acc = __builtin_amdgcn_mfma_f32_16x16x32_bf16(a0.v, hb[0], acc, 0, 0, 0);
    acc = __builtin_amdgcn_mfma_f32_16x16x32_bf16(a1.v, hb[1], acc, 0, 0, 0);
#pragma unroll
    for (int r = 0; r < 4; ++r) ybs[n15][quad * 4 + r] = acc[r];
  }
  const uint4* W4 = (const uint4*)(W2s) + (size_t)q * 16384;
#pragma unroll 4
  for (int tt = 0; tt < 16; ++tt) {
    int t16 = w * 16 + tt;
    uint4 a0 = W4[t16 * 128 + lane];
    uint4 a1 = W4[t16 * 128 + 64 + lane];
    union { uint4 u; bf16x8 v; } c0, c1;
    c0.u = a0; c1.u = a1;
    f32x4 acc = {0.f, 0.f, 0.f, 0.f};
    acc = __builtin_amdgcn_mfma_f32_16x16x32_bf16(c0.v, hb[0], acc, 0, 0, 0);
    acc = __builtin_amdgcn_mfma_f32_16x16x32_bf16(c1.v, hb[1], acc, 0, 0, 0);
    int flat = (t16 * 16 + quad * 4 + n15 * 8) & 2047;
    uint2 pk;
    pk.x = (unsigned)f2b(acc[0]) | ((unsigned)f2b(acc[1]) << 16);
    pk.y = (unsigned)f2b(acc[2]) | ((unsigned)f2b(acc[3]) << 16);
    *(uint2*)&TB[n15 * 2048 + flat] = pk;
  }
  __syncthreads();

  for (int ni = 0; ni < 2; ++ni) {
    int n = w * 2 + ni;
    int v = v0 + n;
    int e0 = offs[v], e1 = offs[v + 1];
    if (e0 >= e1) continue;
    bf16x8 bfr[4];
#pragma unroll
    for (int kb = 0; kb < 4; ++kb) {
      int flat = (((kb * 64 + quad * 16 + n15) << 3) + n * 8) & 2047;
      bfr[kb] = *(const bf16x8*)&TB[n * 2048 + flat];
    }
    float yb = ybs[n][n15];
    for (int jt = e0; jt < e1; jt += 16) {
      int je = jt + n15; if (je > e1 - 1) je = e1 - 1;
      int e = order[je];
      f32x4 acc = {0.f, 0.f, 0.f, 0.f};
#pragma unroll
      for (int kb = 0; kb < 4; ++kb) {
        union { uint4 u; bf16x8 v; } af;
        af.u = *(const uint4*)(r1b + e * 128 + kb * 32 + quad * 8);
        acc = __builtin_amdgcn_mfma_f32_16x16x32_bf16(af.v, bfr[kb], acc, 0, 0, 0);
      }
#pragma unroll
      for (int r = 0; r < 4; ++r) {
        int row = quad * 4 + r;
        if (jt + row < e1) {
          int er = order[jt + row];
          atomicAdd(&agg[dst[er] * 64 + q * 16 + n15], acc[r] + yb);
        }
      }
    }
  }
}

// -------- GRU via MFMA: 1 wave = 16 nodes; resets agg for next step ---------
__global__ __launch_bounds__(64) void k_gru2(
    float* __restrict__ agg, float* __restrict__ h,
    const u16b* __restrict__ WIHf, const u16b* __restrict__ WHHf,
    const float* __restrict__ b_ih, const float* __restrict__ b_hh,
    const float* __restrict__ b_conv) {
  __shared__ float Gr[16][68], Gz[16][68], Gn1[16][68], Gn2[16][68];
  int lane = threadIdx.x;
  int v0 = blockIdx.x * 16;
  int n15 = lane & 15, quad = lane >> 4;
  bf16x8 xB[2], hB[2];
  {
    union { bf16x8 v; u16b s[8]; } bx0, bx1, bh0, bh1;
    float* ap = agg + (v0 + n15) * 64 + quad * 8;
    const float* hp = h + (v0 + n15) * 64 + quad * 8;
    const float* bc = b_conv + quad * 8;
#pragma unroll
    for (int j = 0; j < 8; ++j) {
      bx0.s[j] = f2b(fmaxf(ap[j] + bc[j], 0.f));
      bx1.s[j] = f2b(fmaxf(ap[32 + j] + bc[32 + j], 0.f));
      bh0.s[j] = f2b(hp[j]);
      bh1.s[j] = f2b(hp[32 + j]);
    }
    xB[0] = bx0.v; xB[1] = bx1.v; hB[0] = bh0.v; hB[1] = bh1.v;
    float4 z4 = make_float4(0.f, 0.f, 0.f, 0.f);
    *(float4*)ap = z4; *(float4*)(ap + 4) = z4;
    *(float4*)(ap + 32) = z4; *(float4*)(ap + 36) = z4;
  }
  const uint4* AIH = (const uint4*)WIHf;
  const uint4* AHH = (const uint4*)WHHf;
#pragma unroll
  for (int gt = 0; gt < 8; ++gt) {                // r (0-3) and z (4-7) blocks
    union { uint4 u; bf16x8 v; } a;
    f32x4 acc = {0.f, 0.f, 0.f, 0.f};
    a.u = AIH[(gt * 2 + 0) * 64 + lane];
    acc = __builtin_amdgcn_mfma_f32_16x16x32_bf16(a.v, xB[0], acc, 0, 0, 0);
    a.u = AIH[(gt * 2 + 1) * 64 + lane];
    acc = __builtin_amdgcn_mfma_f32_16x16x32_bf16(a.v, xB[1], acc, 0, 0, 0);
    a.u = AHH[(gt * 2 + 0) * 64 + lane];
    acc = __builtin_amdgcn_mfma_f32_16x16x32_bf16(a.v, hB[0], acc, 0, 0, 0);
    a.u = AHH[(gt * 2 + 1) * 64 + lane];
    acc = __builtin_amdgcn_mfma_f32_16x16x32_bf16(a.v, hB[1], acc, 0, 0, 0);
    float (*dstA)[68] = (gt < 4) ? Gr : Gz;
    int base = (gt & 3) * 16 + quad * 4;
#pragma unroll
    for (int r = 0; r < 4; ++r) dstA[n15][base + r] = acc[r];
  }
#pragma unroll
  for (int gt = 8; gt < 12; ++gt) {               // n block: keep i/h separate
    union { uint4 u; bf16x8 v; } a;
    f32x4 ai = {0.f, 0.f, 0.f, 0.f}, ah = {0.f, 0.f, 0.f, 0.f};
    a.u = AIH[(gt * 2 + 0) * 64 + lane];
    ai = __builtin_amdgcn_mfma_f32_16x16x32_bf16(a.v, xB[0], ai, 0, 0, 0);
    a.u = AIH[(gt * 2 + 1) * 64 + lane];
    ai = __builtin_amdgcn_mfma_f32_16x16x32_bf16(a.v, xB[1], ai, 0, 0, 0);
    a.u = AHH[(gt * 2 + 0) * 64 + lane];
    ah = __builtin_amdgcn_mfma_f32_16x16x32_bf16(a.v, hB[0], ah, 0, 0, 0);
    a.u = AHH[(gt * 2 + 1) * 64 + lane];
    ah = __builtin_amdgcn_mfma_f32_16x16x32_bf16(a.v, hB[1], ah, 0, 0, 0);
    int base = (gt & 3) * 16 + quad * 4;
#pragma unroll
    for (int r = 0; r < 4; ++r) { Gn1[n15][base + r] = ai[r]; Gn2[n15][base + r] = ah[r]; }
  }
  __syncthreads();
  float bi_r = b_ih[lane] + b_hh[lane];
  float bi_z = b_ih[64 + lane] + b_hh[64 + lane];
  float bi_n1 = b_ih[128 + lane], bi_n2 = b_hh[128 + lane];
  for (int n = 0; n < 16; ++n) {
    float r = sigf(Gr[n][lane] + bi_r);
    float z = sigf(Gz[n][lane] + bi_z);
    float nn = tanhf(Gn1[n][lane] + bi_n1 + r * (Gn2[n][lane] + bi_n2));
    float hold = h[(v0 + n) * 64 + lane];
    h[(v0 + n) * 64 + lane] = (1.f - z) * nn + z * hold;
  }
}

// ------- Set2Set: contiguous state window S[320], 8 barriers/iter -----------
__global__ __launch_bounds__(512) void k_s2s(
    const float* __restrict__ h,
    const unsigned* __restrict__ WP0, const unsigned* __restrict__ WP1,
    const unsigned* __restrict__ WP2, const float* __restrict__ bsum,
    const float* __restrict__ W_p1, const float* __restrict__ b_p1,
    const float* __restrict__ W_p2, const float* __restrict__ b_p2,
    float* __restrict__ out) {
  int g = blockIdx.x, t = threadIdx.x;            // 512 threads
  int tt = t & 255, half = t >> 8;
  __shared__ float hL[NPG * 65];
  __shared__ float S[320];                        // [q_star(128)|hs0|hs1|hs2]
  __shared__ float csL[3][64];
  __shared__ float gpart[512], att[NPG];
  unsigned w0[48], w1[32], w2[32];
#pragma unroll
  for (int kk = 0; kk < 48; ++kk) w0[kk] = WP0[(half * 48 + kk) * 256 + tt];
#pragma unroll
  for (int kk = 0; kk < 32; ++kk) w1[kk] = WP1[(half * 32 + kk) * 256 + tt];
#pragma unroll
  for (int kk = 0; kk < 32; ++kk) w2[kk] = WP2[(half * 32 + kk) * 256 + tt];
  for (int idx = t; idx < NPG * 64; idx += 512)
    hL[(idx >> 6) * 65 + (idx & 63)] = h[(size_t)g * NPG * 64 + idx];
  if (t < 320) S[t] = 0.f;
  if (t < 192) ((float*)csL)[t] = 0.f;
  __syncthreads();
  for (int it = 0; it < S2S_ITERS; ++it) {
    // ---- layer 0: window S+0 (len 192) ----
    {
      const float* win = S + half * 96;
      float p = 0.f;
#pragma unroll
      for (int kk = 0; kk < 48; ++kk) {
        unsigned wv = w0[kk];
        p += b2f((u16b)(wv & 0xffffu)) * win[2 * kk]
           + b2f((u16b)(wv >> 16)) * win[2 * kk + 1];
      }
      gpart[t] = p;
    }
    __syncthreads();
    if (t < 64) {
      float gi = bsum[t]       + gpart[t]       + gpart[t + 256];
      float gf = bsum[64 + t]  + gpart[64 + t]  + gpart[64 + t + 256];
      float gg = bsum[128 + t] + gpart[128 + t] + gpart[128 + t + 256];
      float go = bsum[192 + t] + gpart[192 + t] + gpart[192 + t + 256];
      float c = sigf(gf) * csL[0][t] + sigf(gi) * tanhf(gg);
      csL[0][t] = c;
      S[128 + t] = sigf(go) * tanhf(c);
    }
    __syncthreads();
    // ---- layer 1: window S+128 (len 128) ----
    {
      const float* win = S + 128 + half * 64;
      float p = 0.f;
#pragma unroll
      for (int kk = 0; kk < 32; ++kk) {
        unsigned wv = w1[kk];
        p += b2f((u16b)(wv & 0xffffu)) * win[2 * kk]
           + b2f((u16b)(wv >> 16)) * win[2 * kk + 1];
      }
      gpart[t] = p;
    }
    __syncthreads();
    if (t < 64) {
      float gi = bsum[256 + t]       + gpart[t]       + gpart[t + 256];
      float gf = bsum[256 + 64 + t]  + gpart[64 + t]  + gpart[64 + t + 256];
      float gg = bsum[256 + 128 + t] + gpart[128 + t] + gpart[128 + t + 256];
      float go = bsum[256 + 192 + t] + gpart[192 + t] + gpart[192 + t + 256];
      float c = sigf(gf) * csL[1][t] + sigf(gi) * tanhf(gg);
      csL[1][t] = c;
      S[192 + t] = sigf(go) * tanhf(c);
    }
    __syncthreads();
    // ---- layer 2: window S+192 (len 128) ----
    {
      const float* win = S + 192 + half * 64;
      float p = 0.f;
#pragma unroll
      for (int kk = 0; kk < 32; ++kk) {
        unsigned wv = w2[kk];
        p += b2f((u16b)(wv & 0xffffu)) * win[2 * kk]
           + b2f((u16b)(wv >> 16)) * win[2 * kk + 1];
      }
      gpart[t] = p;
    }
    __syncthreads();
    if (t < 64) {
      float gi = bsum[512 + t]       + gpart[t]       + gpart[t + 256];
      float gf = bsum[512 + 64 + t]  + gpart[64 + t]  + gpart[64 + t + 256];
      float gg = bsum[512 + 128 + t] + gpart[128 + t] + gpart[128 + t + 256];
      float go = bsum[512 + 192 + t] + gpart[192 + t] + gpart[192 + t + 256];
      float c = sigf(gf) * csL[2][t] + sigf(gi) * tanhf(gg);
      csL[2][t] = c;
      S[256 + t] = sigf(go) * tanhf(c);
    }
    __syncthreads();
    // ---- attention scores (threads 0..99) ----
    if (t < NPG) {
      float e = 0.f;
#pragma unroll 8
      for (int dd = 0; dd < D; ++dd) e += hL[t * 65 + dd] * S[256 + dd];
      att[t] = e;
    }
    __syncthreads();
    // ---- wave 0: softmax + readout + q_star update (wave-synchronous) ----
    if (t < 64) {
      float m = att[t];
      if (t < NPG - 64) m = fmaxf(m, att[t + 64]);
#pragma unroll
      for (int off = 32; off >= 1; off >>= 1) m = fmaxf(m, __shfl_xor(m, off));
      float e1 = expf(att[t] - m);
      float e2 = (t < NPG - 64) ? expf(att[t + 64] - m) : 0.f;
      att[t] = e1;
      if (t < NPG - 64) att[t + 64] = e2;
      float s = e1 + e2;
#pragma unroll
      for (int off = 32; off >= 1; off >>= 1) s += __shfl_xor(s, off);
      float inv = 1.f / s;
      float r = 0.f;
      for (int n = 0; n < NPG; ++n) r += att[n] * hL[n * 65 + t];
      S[t] = S[256 + t];                          // q
      S[64 + t] = r * inv;                        // readout
    }
    __syncthreads();
  }
  // predict: relu(q_star @ W_p1 + b_p1) @ W_p2 + b_p2
  if (t < 64) {
    float p = b_p1[t];
    for (int k = 0; k < 2 * D; ++k) p += S[k] * W_p1[k * D + t];
    p = fmaxf(p, 0.f);
    att[t] = p * W_p2[t];
  }
  __syncthreads();
  if (t == 0) {
    float s = 0.f;
    for (int j = 0; j < D; ++j) s += att[j];
    out[g] = s + b_p2[0];
  }
}

extern "C" void kernel_launch(void* const* d_in, const int* in_sizes, int n_in,
                              void* d_out, int out_size, void* d_ws, size_t ws_size,
                              hipStream_t stream) {
  const float* node_feats = (const float*)d_in[0];
  const float* edge_feats = (const float*)d_in[1];
  const int*   src        = (const int*)d_in[2];
  const int*   dst        = (const int*)d_in[3];
  // d_in[4] graph_ids: contiguous 100-node segments by construction
  const float* W_proj = (const float*)d_in[5];
  const float* b_proj = (const float*)d_in[6];
  const float* W_e1   = (const float*)d_in[7];
  const float* b_e1   = (const float*)d_in[8];
  const float* W_e2   = (const float*)d_in[9];
  const float* b_e2   = (const float*)d_in[10];
  const float* b_conv = (const float*)d_in[11];
  const float* W_ih   = (const float*)d_in[12];
  const float* W_hh   = (const float*)d_in[13];
  const float* b_ih   = (const float*)d_in[14];
  const float* b_hh   = (const float*)d_in[15];
  const float* Wih0 = (const float*)d_in[16]; const float* Whh0 = (const float*)d_in[17];
  const float* bih0 = (const float*)d_in[18]; const float* bhh0 = (const float*)d_in[19];
  const float* Wih1 = (const float*)d_in[20]; const float* Whh1 = (const float*)d_in[21];
  const float* bih1 = (const float*)d_in[22]; const float* bhh1 = (const float*)d_in[23];
  const float* Wih2 = (const float*)d_in[24]; const float* Whh2 = (const float*)d_in[25];
  const float* bih2 = (const float*)d_in[26]; const float* bhh2 = (const float*)d_in[27];
  const float* W_p1 = (const float*)d_in[28]; const float* b_p1 = (const float*)d_in[29];
  const float* W_p2 = (const float*)d_in[30]; const float* b_p2 = (const float*)d_in[31];

  // ---- workspace layout (total ~13.85 MB; <= proven-safe 14.65 MB) ----
  char* ws = (char*)d_ws;
  float* h      = (float*)(ws + 0);               // 1,024,000
  float* agg    = (float*)(ws + 1024000);         // 1,024,000
  u16b*  r1b    = (u16b*) (ws + 2048000);         // 10,240,000
  int*   offs   = (int*)  (ws + 12288000);        // 16,384 (4096 bins)
  int*   cursor = (int*)  (ws + 12304384);        // 16,384
  int*   order  = (int*)  (ws + 12320768);        // 160,000
  u16b*  W2s    = (u16b*) (ws + 12480768);        // 1,048,576 (fragment-permuted)
  unsigned* WP0 = (unsigned*)(ws + 13529344);     // 98,304
  unsigned* WP1 = (unsigned*)(ws + 13627648);     // 65,536
  unsigned* WP2 = (unsigned*)(ws + 13693184);     // 65,536
  float* bsum   = (float*)(ws + 13758720);        // 3,072
  u16b*  WIHf   = (u16b*) (ws + 13761792);        // 24,576
  u16b*  WHHf   = (u16b*) (ws + 13786368);        // 24,576
  u16b*  W1f    = (u16b*) (ws + 13810944);        // 32,768 -> end 13,843,712

  k_proj<<<V_N, 64, 0, stream>>>(node_feats, W_proj, b_proj, h);
  k_prep<<<2048, 256, 0, stream>>>(W_ih, W_hh, W_e2, W_e1,
      Wih0, Whh0, bih0, bhh0, Wih1, Whh1, bih1, bhh1, Wih2, Whh2, bih2, bhh2,
      W2s, WP0, WP1, WP2, bsum, WIHf, WHHf, W1f);
  k_edge2<<<E_N / 64, 256, 0, stream>>>(edge_feats, W1f, b_e1, r1b);
  // counting sort by src (uses cursor as counts first)
  k_zero<<<16, 256, 0, stream>>>(cursor);
  k_hist<<<(E_N + 255) / 256, 256, 0, stream>>>(src, cursor);
  k_scan<<<1, 256, 0, stream>>>(cursor, offs, cursor);
  k_scatter<<<(E_N + 255) / 256, 256, 0, stream>>>(src, cursor, order);
  k_zero_agg<<<(V_N * D) / 256, 256, 0, stream>>>(agg);

  for (int s = 0; s < NSTEPS; ++s) {
    k_msg7<<<(V_N / 16) * 4, 512, 0, stream>>>(h, r1b, W2s, b_e2,
                                               offs, order, dst, agg);
    k_gru2<<<V_N / 16, 64, 0, stream>>>(agg, h, WIHf, WHHf, b_ih, b_hh, b_conv);
  }
  k_s2s<<<G_N, 512, 0, stream>>>(h, WP0, WP1, WP2, bsum,
      W_p1, b_p1, W_p2, b_p2, (float*)d_out);
}